// Round 17
// baseline (395.567 us; speedup 1.0000x reference)
//
#include <hip/hip_runtime.h>

// Problem constants
#define TT 2048
#define CC 1024
#define NTOK 4096
#define EPSF 1.1920929e-07f

typedef unsigned short u16;
typedef short bf16x8 __attribute__((ext_vector_type(8)));
typedef u16 u16x4 __attribute__((ext_vector_type(4)));
typedef float f32x4 __attribute__((ext_vector_type(4)));

__device__ __forceinline__ u16 f2b(float f) {
  union { float f; unsigned u; } v; v.f = f;
  unsigned r = v.u + 0x7FFFu + ((v.u >> 16) & 1u);
  return (u16)(r >> 16);
}
__device__ __forceinline__ float b2f(u16 u) {
  union { unsigned u; float f; } v; v.u = ((unsigned)u) << 16;
  return v.f;
}
__device__ __forceinline__ void gload16(const u16* g, u16* l) {
  __builtin_amdgcn_global_load_lds(
      (const __attribute__((address_space(1))) void*)g,
      (__attribute__((address_space(3))) void*)l, 16, 0, 0);
}
// swizzled LDS fragment read: tile [R rows][64 u16], phys seg = kseg ^ (row&7)
__device__ __forceinline__ bf16x8 ldsf(const u16* s, int row, int kseg) {
  return *(const bf16x8*)(s + (row << 6) + ((kseg ^ (row & 7)) << 3));
}

// ---------------- RMSNorm -> split bf16 (hi/lo) + fused ve-gates ----------------
// blocks >= NTOK convert QKVO weights to split bf16 (256 8-float chunks each).
__global__ __launch_bounds__(256) void rmsnorm_split_k(const float* __restrict__ in,
                                                       u16* __restrict__ hio,
                                                       u16* __restrict__ loo,
                                                       const float* __restrict__ gW,
                                                       float* __restrict__ gates,
                                                       const float* __restrict__ p0,
                                                       const float* __restrict__ p1,
                                                       const float* __restrict__ p2,
                                                       const float* __restrict__ p3,
                                                       u16* __restrict__ h0, u16* __restrict__ l0,
                                                       u16* __restrict__ h1, u16* __restrict__ l1,
                                                       u16* __restrict__ h2, u16* __restrict__ l2,
                                                       u16* __restrict__ h3, u16* __restrict__ l3) {
  const int bid = blockIdx.x;
  const int t = threadIdx.x;
  if (bid >= NTOK) {
    int chunk = (bid - NTOK) * 256 + t;
    const float* inw; u16* ho; u16* lo2; int loc;
    if (chunk < 131072)      { inw = p0; ho = h0; lo2 = l0; loc = chunk; }
    else if (chunk < 163840) { inw = p1; ho = h1; lo2 = l1; loc = chunk - 131072; }
    else if (chunk < 196608) { inw = p2; ho = h2; lo2 = l2; loc = chunk - 163840; }
    else                     { inw = p3; ho = h3; lo2 = l3; loc = chunk - 196608; }
    size_t i = (size_t)loc * 8;
    float v[8];
    *(float4*)v = *(const float4*)(inw + i);
    *(float4*)(v + 4) = *(const float4*)(inw + i + 4);
    u16 hh[8], ll[8];
#pragma unroll
    for (int j = 0; j < 8; ++j) {
      hh[j] = f2b(v[j]);
      ll[j] = f2b(v[j] - b2f(hh[j]));
    }
    *(bf16x8*)(ho + i) = *(bf16x8*)hh;
    *(bf16x8*)(lo2 + i) = *(bf16x8*)ll;
    return;
  }
  const int rowi = bid;
  float4 v = ((const float4*)(in + (size_t)rowi * CC))[t];
  float ss = v.x * v.x + v.y * v.y + v.z * v.z + v.w * v.w;
#pragma unroll
  for (int off = 32; off; off >>= 1) ss += __shfl_down(ss, off, 64);
  __shared__ float red[4];
  __shared__ float hshare[32];
  if ((t & 63) == 0) red[t >> 6] = ss;
  __syncthreads();
  float tot = red[0] + red[1] + red[2] + red[3];
  float sc = rsqrtf(tot * (1.0f / CC) + EPSF);
  float o[4] = {v.x * sc, v.y * sc, v.z * sc, v.w * sc};
  u16 h[4], l[4];
#pragma unroll
  for (int j = 0; j < 4; ++j) {
    h[j] = f2b(o[j]);
    l[j] = f2b(o[j] - b2f(h[j]));
  }
  *(u16x4*)(hio + (size_t)rowi * CC + t * 4) = *(u16x4*)h;
  *(u16x4*)(loo + (size_t)rowi * CC + t * 4) = *(u16x4*)l;
  if (t < 8) *(float4*)&hshare[t << 2] = *(float4*)o;
  __syncthreads();
  if (t < 4) {
    const float* gw = gW + (t << 5);
    float dot = 0.f;
#pragma unroll
    for (int j = 0; j < 32; ++j) dot += hshare[j] * gw[j];
    gates[(rowi << 2) + t] = 2.f / (1.f + __expf(-dot));
  }
}

// ---------------- RMSNorm(x2) -> bf16 h2 + fp32 router logits ----------------
__global__ __launch_bounds__(256) void rmsnorm_logits_k(const float* __restrict__ in,
                                                        u16* __restrict__ b16o,
                                                        const float* __restrict__ rW,
                                                        float* __restrict__ logits) {
  const int rowi = blockIdx.x;
  const int t = threadIdx.x;
  float4 v = ((const float4*)(in + (size_t)rowi * CC))[t];
  float ss = v.x * v.x + v.y * v.y + v.z * v.z + v.w * v.w;
#pragma unroll
  for (int off = 32; off; off >>= 1) ss += __shfl_down(ss, off, 64);
  __shared__ float red[4];
  __shared__ float red2[8][4];
  if ((t & 63) == 0) red[t >> 6] = ss;
  __syncthreads();
  float tot = red[0] + red[1] + red[2] + red[3];
  float sc = rsqrtf(tot * (1.0f / CC) + EPSF);
  float o[4] = {v.x * sc, v.y * sc, v.z * sc, v.w * sc};
  u16 h[4] = {f2b(o[0]), f2b(o[1]), f2b(o[2]), f2b(o[3])};
  *(u16x4*)(b16o + (size_t)rowi * CC + t * 4) = *(u16x4*)h;
  const float* rwp = rW + (t << 2);
  float part[8];
#pragma unroll
  for (int e = 0; e < 8; ++e) {
    const float* w = rwp + (e << 10);
    part[e] = o[0] * w[0] + o[1] * w[1] + o[2] * w[2] + o[3] * w[3];
  }
  const int wid = t >> 6;
#pragma unroll
  for (int e = 0; e < 8; ++e) {
    float p = part[e];
#pragma unroll
    for (int off = 32; off; off >>= 1) p += __shfl_down(p, off, 64);
    if ((t & 63) == 0) red2[e][wid] = p;
  }
  __syncthreads();
  if (t < 8) logits[rowi * 8 + t] = red2[t][0] + red2[t][1] + red2[t][2] + red2[t][3];
}

// ---------------- bf16 MFMA GEMM: C[M,N] = A[M,K] @ W[N,K]^T ----------------
// SPLIT modes (6, 11): 64x64 tile, 4 waves of 16x64 (acc[1][4]), hi/lo 3-MFMA, 32 KB LDS.
// Non-split modes (4, 5): 128x64 tile, 4 waves of 32x64 (acc[2][4]), 24 KB LDS.
// Per-output-element K-accumulation order identical in both tilings (bit-identical outputs).
// MODE:
// 4 gathered A, relu^2 bf16 out (expert fc; e==8 -> shared: identity gather, Wk1 weights)
// 5 gathered rows, w*atomicAdd f32 (expert proj; e==8 -> shared: w=1, Wk1 weights)
// 6 split(3-mfma), f32 x2 = v+addv, also pre-init out ((float*)Cb)
// 11 split fused QKV: N=1536 col-space; Q->rope+rms, K->rope+rms, V->gate (transposed store)
template <int MODE>
__global__ __launch_bounds__(256) void gemm_bf_k(
    const u16* __restrict__ A, const u16* __restrict__ A2,
    const u16* __restrict__ Wt, const u16* __restrict__ W2,
    const u16* __restrict__ Wk1, const u16* __restrict__ Wk2,
    const u16* __restrict__ Wv1, const u16* __restrict__ Wv2,
    float* __restrict__ Cf, u16* __restrict__ Cb,
    u16* __restrict__ Ck, u16* __restrict__ Cv,
    const float* __restrict__ addv, int N, int K,
    const int* __restrict__ offsets, const int* __restrict__ counts,
    const int* __restrict__ tok_idx, const float* __restrict__ tok_w,
    const float* __restrict__ cosb, const float* __restrict__ sinb,
    const float* __restrict__ gates, const float* __restrict__ vein) {
  constexpr bool SPLIT = (MODE == 6 || MODE == 11);
  constexpr int NAG = SPLIT ? 2 : 4;   // A staging groups of 32 rows
  constexpr int NMI = SPLIT ? 1 : 2;   // 16-row fragments per wave
  __shared__ __align__(16) u16 Asw[8192];
  __shared__ __align__(16) u16 Bsw[SPLIT ? 8192 : 4096];
  const int t = threadIdx.x;
  const int lane = t & 63;
  const int l15 = lane & 15, hi = lane >> 4;
  const int wave = t >> 6;
  const int e = blockIdx.z;
  const int mt = blockIdx.y << (SPLIT ? 6 : 7);
  const int bn = blockIdx.x << 6;
  int base = 0, cnt = 0;
  if (MODE == 4 || MODE == 5) {
    cnt = (e == 8) ? NTOK : counts[e];
    if (mt >= cnt) return;
    base = (e == 8) ? 8192 : offsets[e];
  }
  const int r8 = t >> 3;
  const int ksg = (t & 7) ^ (r8 & 7);  // inverse-swizzled global k-segment
  const u16* asrc[NAG];
  const u16* bsrc[2];
  const u16* asrc2[NAG];
  const u16* bsrc2[2];
  // weight selection
  const u16* W1p = Wt;
  if (MODE == 4 || MODE == 5) W1p = (e == 8) ? Wk1 : Wt + ((size_t)e << 20);
  const u16* W2p = W2;
  int wrow = bn;
  if (MODE == 11) {
    if (bn >= 1280)      { W1p = Wv1; W2p = Wv2; wrow = bn - 1280; }
    else if (bn >= 1024) { W1p = Wk1; W2p = Wk2; wrow = bn - 1024; }
  }
#pragma unroll
  for (int g = 0; g < NAG; ++g) {
    int rl = (g << 5) + r8;
    int arow;
    if (MODE == 4) {
      int rr = mt + rl; if (rr > cnt - 1) rr = cnt - 1;
      arow = (e == 8) ? rr : tok_idx[base + rr];
    } else if (MODE == 5) {
      int rr = mt + rl; if (rr > cnt - 1) rr = cnt - 1;
      arow = base + rr;
    } else {
      arow = mt + rl;
    }
    size_t ao = (size_t)arow * K + (ksg << 3);
    asrc[g] = A + ao;
    if (SPLIT) asrc2[g] = A2 + ao;
  }
#pragma unroll
  for (int g = 0; g < 2; ++g) {
    size_t bo = (size_t)(wrow + (g << 5) + r8) * K + (ksg << 3);
    bsrc[g] = W1p + bo;
    if (SPLIT) bsrc2[g] = W2p + bo;
  }
  f32x4 acc[NMI][4] = {};
  const int nkt = K >> 6;
  for (int kt = 0; kt < nkt; ++kt) {
    __syncthreads();
    const int ko = kt << 6;
#pragma unroll
    for (int g = 0; g < NAG; ++g) {
      int co = ((g << 8) + t) << 3;
      gload16(asrc[g] + ko, &Asw[co]);
      if (SPLIT) gload16(asrc2[g] + ko, &Asw[4096 + co]);
    }
#pragma unroll
    for (int g = 0; g < 2; ++g) {
      int co = ((g << 8) + t) << 3;
      gload16(bsrc[g] + ko, &Bsw[co]);
      if (SPLIT) gload16(bsrc2[g] + ko, &Bsw[4096 + co]);
    }
    __syncthreads();
#pragma unroll
    for (int kk = 0; kk < 2; ++kk) {
      bf16x8 ah[NMI], bh[4];
#pragma unroll
      for (int mi = 0; mi < NMI; ++mi)
        ah[mi] = ldsf(Asw, (SPLIT ? (wave << 4) : ((wave << 5) + (mi << 4))) + l15, (kk << 2) + hi);
#pragma unroll
      for (int nj = 0; nj < 4; ++nj)
        bh[nj] = ldsf(Bsw, (nj << 4) + l15, (kk << 2) + hi);
#pragma unroll
      for (int mi = 0; mi < NMI; ++mi)
#pragma unroll
        for (int nj = 0; nj < 4; ++nj)
          acc[mi][nj] = __builtin_amdgcn_mfma_f32_16x16x32_bf16(ah[mi], bh[nj], acc[mi][nj], 0, 0, 0);
      if (SPLIT) {
        bf16x8 al[NMI], bl[4];
#pragma unroll
        for (int mi = 0; mi < NMI; ++mi)
          al[mi] = ldsf(Asw + 4096, (wave << 4) + l15, (kk << 2) + hi);
#pragma unroll
        for (int nj = 0; nj < 4; ++nj)
          bl[nj] = ldsf(Bsw + 4096, (nj << 4) + l15, (kk << 2) + hi);
#pragma unroll
        for (int mi = 0; mi < NMI; ++mi)
#pragma unroll
          for (int nj = 0; nj < 4; ++nj) {
            acc[mi][nj] = __builtin_amdgcn_mfma_f32_16x16x32_bf16(ah[mi], bl[nj], acc[mi][nj], 0, 0, 0);
            acc[mi][nj] = __builtin_amdgcn_mfma_f32_16x16x32_bf16(al[mi], bh[nj], acc[mi][nj], 0, 0, 0);
          }
      }
    }
  }
  // ---- epilogues (C/D layout: col=l15, row=hi*4+r; block col span = bn..bn+63) ----
  if (MODE == 11) {
    if (bn < 1280) {
      // rope + per-head rmsnorm (Q or K); block's 64 cols = one head
      u16* outp = (bn < 1024) ? Cb : Ck;
      const int stride = (bn < 1024) ? 1024 : 256;
      const int cbase = (bn < 1024) ? bn : (bn - 1024);
#pragma unroll
      for (int r = 0; r < 4; ++r) {
        int row = mt + (wave << 4) + (hi << 2) + r;
        int tpos = row & (TT - 1);
        const float* cp = cosb + (tpos << 5);
        const float* sp = sinb + (tpos << 5);
        float c0 = cp[l15], s0 = sp[l15];
        float c1 = cp[16 + l15], s1 = sp[16 + l15];
        float a0 = acc[0][0][r], a1 = acc[0][1][r];
        float b0 = acc[0][2][r], b1 = acc[0][3][r];
        float r00 = a0 * c0 + b0 * s0;
        float r01 = a1 * c1 + b1 * s1;
        float r10 = b0 * c0 - a0 * s0;
        float r11 = b1 * c1 - a1 * s1;
        float ss = r00 * r00 + r01 * r01 + r10 * r10 + r11 * r11;
        ss += __shfl_xor(ss, 1, 64); ss += __shfl_xor(ss, 2, 64);
        ss += __shfl_xor(ss, 4, 64); ss += __shfl_xor(ss, 8, 64);
        float scn = rsqrtf(ss * (1.f / 64.f) + EPSF);
        u16* qp = outp + (size_t)row * stride + cbase;
        qp[l15]      = f2b(r00 * scn);
        qp[16 + l15] = f2b(r01 * scn);
        qp[32 + l15] = f2b(r10 * scn);
        qp[48 + l15] = f2b(r11 * scn);
      }
    } else {
      // V: gate epilogue, store TRANSPOSED: Cv[((b*4+kvh)*64 + d)*2048 + tok_in_b]
      const int cbase = bn - 1280;
      const int kvh = cbase >> 6;
#pragma unroll
      for (int r = 0; r < 4; ++r) {
        int row = mt + (wave << 4) + (hi << 2) + r;
        float g = gates[(row << 2) + kvh];
        const float* vep = vein + ((size_t)row << 8) + cbase;
        size_t vb_base = ((size_t)(((row >> 11) << 2) + kvh) << 17) + (row & (TT - 1));
#pragma unroll
        for (int nj = 0; nj < 4; ++nj) {
          int d = (nj << 4) + l15;
          Cv[vb_base + ((size_t)d << 11)] = f2b(acc[0][nj][r] + g * vep[d]);
        }
      }
    }
    return;
  }
#pragma unroll
  for (int mi = 0; mi < NMI; ++mi) {
#pragma unroll
    for (int r = 0; r < 4; ++r) {
      int rl = (SPLIT ? (wave << 4) : ((wave << 5) + (mi << 4))) + (hi << 2) + r;
      if (MODE == 4 || MODE == 5) {
        int rr = mt + rl;
        if (rr >= cnt) continue;
        if (MODE == 4) {
          size_t ro = (size_t)(base + rr) * N;
#pragma unroll
          for (int nj = 0; nj < 4; ++nj) {
            float v = acc[mi][nj][r];
            v = v > 0.f ? v * v : 0.f;
            Cb[ro + bn + (nj << 4) + l15] = f2b(v);
          }
        } else {
          int tok = (e == 8) ? rr : tok_idx[base + rr];
          float w = (e == 8) ? 1.0f : tok_w[base + rr];
          size_t ro = (size_t)tok * N;
#pragma unroll
          for (int nj = 0; nj < 4; ++nj)
            atomicAdd(&Cf[ro + bn + (nj << 4) + l15], acc[mi][nj][r] * w);
        }
      } else {  // MODE 6
        size_t ro = (size_t)(mt + rl) * N;
        float* outp = (float*)Cb;
#pragma unroll
        for (int nj = 0; nj < 4; ++nj) {
          int col = bn + (nj << 4) + l15;
          float v = acc[mi][nj][r] + addv[ro + col];
          Cf[ro + col] = v;
          outp[ro + col] = v;
        }
      }
    }
  }
}

// ---------------- flash attention, split-K, dbuf K/V staging; idle blocks convert weights ----------------
// FROZEN NUMERICS: max-tracked online softmax, exact op order from rounds 13/15/16 (passing).
// grid = (128 q-frags, 4 kvh, 4 = b*2+seg), 256 threads = 4 waves; wave w = head kvh*4+w.
// The 512 (qf<64, seg=1) blocks convert shared/expert weights (hidden under attn).
__global__ __launch_bounds__(256) void attn_mfma_k(const u16* __restrict__ qb,
                                                   const u16* __restrict__ kb,
                                                   const u16* __restrict__ vbT,
                                                   u16* __restrict__ yh,
                                                   u16* __restrict__ yl,
                                                   const int* __restrict__ wszp,
                                                   float* __restrict__ po,
                                                   float* __restrict__ pml,
                                                   const float* __restrict__ cSfc,
                                                   const float* __restrict__ cSproj,
                                                   const float* __restrict__ cEfc,
                                                   const float* __restrict__ cEproj,
                                                   u16* __restrict__ oSfc,
                                                   u16* __restrict__ oSproj,
                                                   u16* __restrict__ oEfc,
                                                   u16* __restrict__ oEproj) {
  const int z = blockIdx.z;
  const int b = z >> 1, seg = z & 1;
  const int kvh = blockIdx.y;
  const int qf = 127 - (int)blockIdx.x;  // LPT: longest first
  const int t = threadIdx.x;
  if (qf < 64 && seg) {
    // converter block: 4608 chunks of 8 floats each (18 iters x 256 threads)
    const int cid = (((b << 2) + kvh) << 6) + ((int)blockIdx.x - 64);
    int chunk = cid * 4608 + t;
#pragma unroll
    for (int it = 0; it < 18; ++it, chunk += 256) {
      const float* in;
      u16* ou;
      int loc;
      if (chunk < 131072)       { in = cSfc;   ou = oSfc;   loc = chunk; }
      else if (chunk < 262144)  { in = cSproj; ou = oSproj; loc = chunk - 131072; }
      else if (chunk < 1310720) { in = cEfc;   ou = oEfc;   loc = chunk - 262144; }
      else                      { in = cEproj; ou = oEproj; loc = chunk - 1310720; }
      size_t i = (size_t)loc * 8;
      float4 a = *(const float4*)(in + i);
      float4 bb = *(const float4*)(in + i + 4);
      u16 r[8] = {f2b(a.x), f2b(a.y), f2b(a.z), f2b(a.w),
                  f2b(bb.x), f2b(bb.y), f2b(bb.z), f2b(bb.w)};
      *(bf16x8*)(ou + i) = *(bf16x8*)r;
    }
    return;
  }
  const int Wn = *wszp;
  const int lane = t & 63, wave = t >> 6;
  const int h = (kvh << 2) + wave;
  const int l15 = lane & 15, hi = lane >> 4;

  __shared__ __align__(16) u16 Klds[2 * 4096];    // dbuf swizzled [key][d]
  __shared__ __align__(16) u16 Vt[2 * 4096];      // dbuf swizzled [d][key]
  __shared__ __align__(16) u16 Plds[4][16 * 64];  // per-wave swizzled [qrow][key]

  const int qrow0 = qf << 4;
  const int diag = qrow0 >> 6;
  int lo = qrow0 - Wn + 1;
  const int kt0f = lo > 0 ? (lo >> 6) : 0;
  int kt0 = kt0f, ktend = diag;
  if (qf >= 64) {
    int nt = diag - kt0f + 1;
    int mid = kt0f + (nt >> 1);
    if (seg == 0) ktend = mid - 1; else kt0 = mid;
  }

  bf16x8 aQ0, aQ1;
  {
    const u16* qp = qb + ((size_t)((b << 11) + qrow0 + l15) << 10) + (h << 6) + (hi << 3);
    aQ0 = *(const bf16x8*)qp;
    aQ1 = *(const bf16x8*)(qp + 32);
  }
  f32x4 o[4] = {};
  float mrow[4] = {-INFINITY, -INFINITY, -INFINITY, -INFINITY};
  float lrow[4] = {0.f, 0.f, 0.f, 0.f};

  const int kr0 = t >> 3, kc = t & 7;  // staging coords (row 0..31, 8-elem col chunk)
  const u16* vbase = vbT + ((size_t)((b << 2) + kvh) << 17);

  // prologue: stage kt0 into buf 0
#pragma unroll
  for (int i = 0; i < 2; ++i) {
    int row = kr0 + (i << 5);
    int scol = (kc ^ (row & 7)) << 3;
    gload16(kb + ((size_t)((b << 11) + (kt0 << 6) + row) << 8) + (kvh << 6) + scol,
            &Klds[(t << 3) + (i << 11)]);
    gload16(vbase + ((size_t)row << 11) + (kt0 << 6) + scol,
            &Vt[(t << 3) + (i << 11)]);
  }
  int cur = 0;

  for (int kt = kt0; kt <= ktend; ++kt) {
    __syncthreads();  // buf[cur] loads drained; prior reads of buf[cur^1] retired
    if (kt + 1 <= ktend) {
      const int nb = (cur ^ 1) << 12;
#pragma unroll
      for (int i = 0; i < 2; ++i) {
        int row = kr0 + (i << 5);
        int scol = (kc ^ (row & 7)) << 3;
        gload16(kb + ((size_t)((b << 11) + ((kt + 1) << 6) + row) << 8) + (kvh << 6) + scol,
                &Klds[nb + (t << 3) + (i << 11)]);
        gload16(vbase + ((size_t)row << 11) + ((kt + 1) << 6) + scol,
                &Vt[nb + (t << 3) + (i << 11)]);
      }
    }
    const u16* Kb = Klds + (cur << 12);
    const u16* Vb = Vt + (cur << 12);

    // QK^T (setprio around MFMA cluster)
    float sv[4][4];
    __builtin_amdgcn_s_setprio(1);
#pragma unroll
    for (int kb4 = 0; kb4 < 4; ++kb4) {
      f32x4 S = {0.f, 0.f, 0.f, 0.f};
      bf16x8 B0 = ldsf(Kb, (kb4 << 4) + l15, hi);
      bf16x8 B1 = ldsf(Kb, (kb4 << 4) + l15, 4 + hi);
      S = __builtin_amdgcn_mfma_f32_16x16x32_bf16(aQ0, B0, S, 0, 0, 0);
      S = __builtin_amdgcn_mfma_f32_16x16x32_bf16(aQ1, B1, S, 0, 0, 0);
#pragma unroll
      for (int r = 0; r < 4; ++r) sv[kb4][r] = S[r] * 0.125f;
    }
    __builtin_amdgcn_s_setprio(0);
    // masking only on diagonal / window-edge tiles (wave-uniform branch)
    if (kt == diag || kt == kt0f) {
#pragma unroll
      for (int kb4 = 0; kb4 < 4; ++kb4) {
        int key = (kt << 6) + (kb4 << 4) + l15;
#pragma unroll
        for (int r = 0; r < 4; ++r) {
          int qg = qrow0 + (hi << 2) + r;
          if (!(key <= qg && key > qg - Wn)) sv[kb4][r] = -INFINITY;
        }
      }
    }

    // online softmax (4 independent chains), guard-free exp
    float scl[4], pv[4][4];
#pragma unroll
    for (int r = 0; r < 4; ++r) {
      float mt2 = fmaxf(fmaxf(sv[0][r], sv[1][r]), fmaxf(sv[2][r], sv[3][r]));
      mt2 = fmaxf(mt2, __shfl_xor(mt2, 1, 64));
      mt2 = fmaxf(mt2, __shfl_xor(mt2, 2, 64));
      mt2 = fmaxf(mt2, __shfl_xor(mt2, 4, 64));
      mt2 = fmaxf(mt2, __shfl_xor(mt2, 8, 64));
      float mn = fmaxf(fmaxf(mrow[r], mt2), -1e30f);
      float sc = __expf(mrow[r] - mn);
      float rs = 0.f;
#pragma unroll
      for (int kb4 = 0; kb4 < 4; ++kb4) {
        float p = __expf(sv[kb4][r] - mn);
        pv[kb4][r] = p;
        rs += p;
      }
      rs += __shfl_xor(rs, 1, 64);
      rs += __shfl_xor(rs, 2, 64);
      rs += __shfl_xor(rs, 4, 64);
      rs += __shfl_xor(rs, 8, 64);
      mrow[r] = mn;
      lrow[r] = lrow[r] * sc + rs;
      scl[r] = sc;
    }

    // P -> wave-local swizzled LDS
#pragma unroll
    for (int kb4 = 0; kb4 < 4; ++kb4)
#pragma unroll
      for (int r = 0; r < 4; ++r) {
        int row16 = (hi << 2) + r;
        int seg2 = (kb4 << 1) + (l15 >> 3);
        Plds[wave][(row16 << 6) + ((seg2 ^ (row16 & 7)) << 3) + (l15 & 7)] = f2b(pv[kb4][r]);
      }
    // rescale O
#pragma unroll
    for (int df = 0; df < 4; ++df) {
      f32x4 t4 = o[df];
      t4[0] *= scl[0]; t4[1] *= scl[1]; t4[2] *= scl[2]; t4[3] *= scl[3];
      o[df] = t4;
    }
    // PV (setprio around MFMA cluster)
    __builtin_amdgcn_s_setprio(1);
#pragma unroll
    for (int ks = 0; ks < 2; ++ks) {
      bf16x8 Ap = ldsf(Plds[wave], l15, (ks << 2) + hi);
#pragma unroll
      for (int df = 0; df < 4; ++df) {
        bf16x8 Bv = ldsf(Vb, (df << 4) + l15, (ks << 2) + hi);
        o[df] = __builtin_amdgcn_mfma_f32_16x16x32_bf16(Ap, Bv, o[df], 0, 0, 0);
      }
    }
    __builtin_amdgcn_s_setprio(0);
    cur ^= 1;
  }

  if (qf < 64) {
    float inv[4];
#pragma unroll
    for (int r = 0; r < 4; ++r) inv[r] = lrow[r] > 0.f ? 1.f / lrow[r] : 0.f;
#pragma unroll
    for (int r = 0; r < 4; ++r) {
      size_t rbase = ((size_t)((b << 11) + qrow0 + (hi << 2) + r) << 10) + (h << 6) + l15;
#pragma unroll
      for (int df = 0; df < 4; ++df) {
        float fo = o[df][r] * inv[r];
        u16 hv = f2b(fo);
        yh[rbase + (df << 4)] = hv;
        yl[rbase + (df << 4)] = f2b(fo - b2f(hv));
      }
    }
  } else {
    const int sidx = (b << 1) + seg;
    const int prow0 = qrow0 - 1024;
#pragma unroll
    for (int r = 0; r < 4; ++r) {
      size_t pbase = ((size_t)(sidx * 1024 + prow0 + (hi << 2) + r) << 10) + (h << 6) + l15;
#pragma unroll
      for (int df = 0; df < 4; ++df) po[pbase + (df << 4)] = o[df][r];
    }
    if (l15 == 0) {
#pragma unroll
      for (int r = 0; r < 4; ++r) {
        size_t mb = ((size_t)(sidx * 1024 + prow0 + (hi << 2) + r) << 5) + (h << 1);
        pml[mb] = mrow[r];
        pml[mb + 1] = lrow[r];
      }
    }
  }
}

// ---------------- combine split-K partials -> y (max-tracked merge) ----------------
__global__ __launch_bounds__(256) void combine_k(const float* __restrict__ po,
                                                 const float* __restrict__ pml,
                                                 u16* __restrict__ yh,
                                                 u16* __restrict__ yl) {
  const int prow = blockIdx.x, b = blockIdx.y;
  const int t = threadIdx.x;
  const int h = t >> 4, d0 = (t & 15) << 2;
  const int s0 = b << 1, s1 = s0 + 1;
  size_t i0 = ((size_t)(s0 * 1024 + prow) << 5) + (h << 1);
  size_t i1 = ((size_t)(s1 * 1024 + prow) << 5) + (h << 1);
  float m0 = pml[i0], l0 = pml[i0 + 1];
  float m1 = pml[i1], l1 = pml[i1 + 1];
  float m = fmaxf(m0, m1);
  float sc0 = __expf(m0 - m), sc1 = __expf(m1 - m);
  float l = l0 * sc0 + l1 * sc1;
  float inv = l > 0.f ? 1.f / l : 0.f;
  size_t o0 = ((size_t)(s0 * 1024 + prow) << 10) + (h << 6) + d0;
  size_t o1 = ((size_t)(s1 * 1024 + prow) << 10) + (h << 6) + d0;
  float4 a = *(const float4*)&po[o0];
  float4 c = *(const float4*)&po[o1];
  float y0 = (a.x * sc0 + c.x * sc1) * inv;
  float y1 = (a.y * sc0 + c.y * sc1) * inv;
  float y2 = (a.z * sc0 + c.z * sc1) * inv;
  float y3 = (a.w * sc0 + c.w * sc1) * inv;
  u16 hv[4] = {f2b(y0), f2b(y1), f2b(y2), f2b(y3)};
  u16 lv[4] = {f2b(y0 - b2f(hv[0])), f2b(y1 - b2f(hv[1])),
               f2b(y2 - b2f(hv[2])), f2b(y3 - b2f(hv[3]))};
  size_t rbase = ((size_t)((b << 11) + 1024 + prow) << 10) + (h << 6) + d0;
  *(u16x4*)(yh + rbase) = *(u16x4*)hv;
  *(u16x4*)(yl + rbase) = *(u16x4*)lv;
}

// ---------------- top-2 router from precomputed logits ----------------
__global__ __launch_bounds__(256) void topk_k(const float* __restrict__ logits,
                                              const float* __restrict__ bias,
                                              int* __restrict__ topi,
                                              float* __restrict__ topw,
                                              int* __restrict__ counts) {
  int n = blockIdx.x * 256 + threadIdx.x;
  if (n >= NTOK) return;
  float sc[8], sel[8];
#pragma unroll
  for (int e2 = 0; e2 < 8; ++e2) {
    float sg = 1.f / (1.f + __expf(-logits[n * 8 + e2]));
    sc[e2] = sg;
    sel[e2] = sg + bias[e2];
  }
  int i1 = 0; float b1 = sel[0];
#pragma unroll
  for (int j = 1; j < 8; ++j) if (sel[j] > b1) { b1 = sel[j]; i1 = j; }
  int i2 = -1; float b2 = -INFINITY;
#pragma unroll
  for (int j = 0; j < 8; ++j) if (j != i1 && sel[j] > b2) { b2 = sel[j]; i2 = j; }
  float w1 = sc[i1], w2 = sc[i2];
  float invs = 1.f / (w1 + w2 + 1e-20f);
  topi[n * 2] = i1; topi[n * 2 + 1] = i2;
  topw[n * 2] = w1 * invs; topw[n * 2 + 1] = w2 * invs;
  atomicAdd(&counts[i1], 1);
  atomicAdd(&counts[i2], 1);
}

__global__ void scan_k(const int* __restrict__ counts, int* __restrict__ offsets) {
  if (threadIdx.x == 0 && blockIdx.x == 0) {
    int s = 0;
    for (int e2 = 0; e2 < 8; ++e2) { offsets[e2] = s; s += counts[e2]; }
    offsets[8] = s;
  }
}

__global__ __launch_bounds__(256) void scatter_k(const int* __restrict__ topi,
                                                 const float* __restrict__ topw,
                                                 const int* __restrict__ offsets,
                                                 int* __restrict__ counts2,
                                                 int* __restrict__ tok_idx,
                                                 float* __restrict__ tok_w) {
  int n = blockIdx.x * 256 + threadIdx.x;
  if (n >= NTOK) return;
  for (int kk = 0; kk < 2; ++kk) {
    int e2 = topi[n * 2 + kk];
    int slot = atomicAdd(&counts2[e2], 1);
    int p = offsets[e2] + slot;
    tok_idx[p] = n;
    tok_w[p] = topw[n * 2 + kk];
  }
}

extern "C" void kernel_launch(void* const* d_in, const int* in_sizes, int n_in,
                              void* d_out, int out_size, void* d_ws, size_t ws_size,
                              hipStream_t stream) {
  const float* x = (const float*)d_in[0];
  const float* ve = (const float*)d_in[1];
  const float* cosb = (const float*)d_in[2];
  const float* sinb = (const float*)d_in[3];
  const float* Wq = (const float*)d_in[4];
  const float* Wk = (const float*)d_in[5];
  const float* Wv = (const float*)d_in[6];
  const float* Wo = (const float*)d_in[7];
  const float* gW = (const float*)d_in[8];
  const float* routerW = (const float*)d_in[9];
  const float* bias = (const float*)d_in[10];
  const float* Wsfc = (const float*)d_in[11];
  const float* Wsproj = (const float*)d_in[12];
  const float* Wefc = (const float*)d_in[13];
  const float* Weproj = (const float*)d_in[14];
  const int* wsz = (const int*)d_in[15];
  float* out = (float*)d_out;
  char* WS = (char*)d_ws;

  // ---- workspace layout (byte offsets), peak ~91 MiB ----
  u16* Wefc_b   = (u16*)(WS + 0);          // 16 MiB
  u16* Weproj_b = (u16*)(WS + 16777216);   // 16 MiB
  u16* Wsfc_b   = (u16*)(WS + 33554432);   // 2 MiB
  u16* Wsproj_b = (u16*)(WS + 35651584);   // 2 MiB
  u16* Wq_hi    = (u16*)(WS + 37748736);   // 2 MiB
  u16* Wq_lo    = (u16*)(WS + 39845888);   // 2 MiB
  u16* Wk_hi    = (u16*)(WS + 41943040);   // 0.5 MiB
  u16* Wk_lo    = (u16*)(WS + 42467328);   // 0.5 MiB
  u16* Wv_hi    = (u16*)(WS + 42991616);   // 0.5 MiB
  u16* Wv_lo    = (u16*)(WS + 43515904);   // 0.5 MiB
  u16* Wo_hi    = (u16*)(WS + 44040192);   // 2 MiB
  u16* Wo_lo    = (u16*)(WS + 46137344);   // 2 MiB
  u16* h_hi     = (u16*)(WS + 48234496);   // 8 MiB [dead after QKV]
  u16* h_lo     = (u16*)(WS + 56623104);   // 8 MiB [dead after QKV]
  u16* qb       = (u16*)(WS + 65011712);   // 8 MiB [dead after attn]
  u16* kb       = (u16*)(WS + 73400320);   // 2 MiB [dead after attn]
  u16* vb       = (u16*)(WS + 75497472);   // 2 MiB [dead after attn] (transposed layout)
  u16* y_hi     = (u16*)(WS + 77594624);   // 8 MiB [dead after Wo gemm]
  u16* y_lo     = (u16*)(WS + 85983232);   // 8 MiB [dead after Wo gemm]
  float* po     = (float*)(WS + 48234496); // 16 MiB over h_hi+h_lo [attn partials; dead after combine]
  float* x2     = (float*)(WS + 48234496); // 16 MiB over po [written post-combine, dead post-logits]
  u16* h2_b     = (u16*)(WS + 85983232);   // 8 MiB over y_lo [written post-Wo]
  u16* he_b     = (u16*)(WS + 48234496);   // 24 MiB over x2+qb [written post-logits], 12288 rows
  float* gates  = (float*)(WS + 94371840); // 64 KiB
  float* logits = (float*)(WS + 94437376); // 128 KiB
  int* meta     = (int*)(WS + 94568448);
  int* counts   = meta;
  int* counts2  = meta + 8;
  int* offsets  = meta + 16;
  int* topi     = meta + 32;
  float* topw   = (float*)(meta + 8224);
  int* tok_idx  = meta + 16416;
  float* tok_w  = (float*)(meta + 24608);
  float* pml    = (float*)(WS + 94703616); // 512 KiB attn partial m/l

  hipMemsetAsync(counts, 0, 16 * sizeof(int), stream);

  // h = rmsnorm(x) split + fused gates; extra 1280 blocks convert QKVO weights (split)
  rmsnorm_split_k<<<NTOK + 1280, 256, 0, stream>>>(x, h_hi, h_lo, gW, gates,
      Wq, Wk, Wv, Wo,
      Wq_hi, Wq_lo, Wk_hi, Wk_lo, Wv_hi, Wv_lo, Wo_hi, Wo_lo);
  // fused QKV split gemm (N=1536, 64x64 tiles) with per-head epilogues (V stored transposed)
  gemm_bf_k<11><<<dim3(24, 64), 256, 0, stream>>>(
      h_hi, h_lo, Wq_hi, Wq_lo, Wk_hi, Wk_lo, Wv_hi, Wv_lo,
      nullptr, qb, kb, vb, nullptr, 1536, 1024,
      nullptr, nullptr, nullptr, nullptr, cosb, sinb, gates, ve);
  // attention (split-K for rows >= 1024) -> y + partials; idle blocks convert expert weights
  attn_mfma_k<<<dim3(128, 4, 4), 256, 0, stream>>>(qb, kb, vb, y_hi, y_lo, wsz, po, pml,
      Wsfc, Wsproj, Wefc, Weproj, Wsfc_b, Wsproj_b, Wefc_b, Weproj_b);
  combine_k<<<dim3(1024, 2), 256, 0, stream>>>(po, pml, y_hi, y_lo);
  // x2 = x + y @ Wo^T (split, 64x64 tiles); also pre-init out = x2
  gemm_bf_k<6><<<dim3(16, 64), 256, 0, stream>>>(
      y_hi, y_lo, Wo_hi, Wo_lo, nullptr, nullptr, nullptr, nullptr,
      x2, (u16*)out, nullptr, nullptr, x, 1024, 1024,
      nullptr, nullptr, nullptr, nullptr, nullptr, nullptr, nullptr, nullptr);
  // h2 = rmsnorm(x2) -> bf16 + fp32 router logits
  rmsnorm_logits_k<<<NTOK, 256, 0, stream>>>(x2, h2_b, routerW, logits);
  // router + bucketing
  topk_k<<<16, 256, 0, stream>>>(logits, bias, topi, topw, counts);
  scan_k<<<1, 64, 0, stream>>>(counts, offsets);
  scatter_k<<<16, 256, 0, stream>>>(topi, topw, offsets, counts2, tok_idx, tok_w);
  // experts (z=8 routed + z==8 shared), 128x64 tiles, fc then proj (atomicAdd into out)
  gemm_bf_k<4><<<dim3(16, 32, 9), 256, 0, stream>>>(
      h2_b, nullptr, Wefc_b, nullptr, Wsfc_b, nullptr, nullptr, nullptr,
      nullptr, he_b, nullptr, nullptr, nullptr, 1024, 1024,
      offsets, counts, tok_idx, nullptr, nullptr, nullptr, nullptr, nullptr);
  gemm_bf_k<5><<<dim3(16, 32, 9), 256, 0, stream>>>(
      he_b, nullptr, Weproj_b, nullptr, Wsproj_b, nullptr, nullptr, nullptr,
      out, nullptr, nullptr, nullptr, nullptr, 1024, 1024,
      offsets, counts, tok_idx, tok_w, nullptr, nullptr, nullptr, nullptr);
}

// Round 18
// 388.862 us; speedup vs baseline: 1.0172x; 1.0172x over previous
//
#include <hip/hip_runtime.h>

// Problem constants
#define TT 2048
#define CC 1024
#define NTOK 4096
#define EPSF 1.1920929e-07f

typedef unsigned short u16;
typedef short bf16x8 __attribute__((ext_vector_type(8)));
typedef u16 u16x4 __attribute__((ext_vector_type(4)));
typedef float f32x4 __attribute__((ext_vector_type(4)));

__device__ __forceinline__ u16 f2b(float f) {
  union { float f; unsigned u; } v; v.f = f;
  unsigned r = v.u + 0x7FFFu + ((v.u >> 16) & 1u);
  return (u16)(r >> 16);
}
__device__ __forceinline__ float b2f(u16 u) {
  union { unsigned u; float f; } v; v.u = ((unsigned)u) << 16;
  return v.f;
}
__device__ __forceinline__ void gload16(const u16* g, u16* l) {
  __builtin_amdgcn_global_load_lds(
      (const __attribute__((address_space(1))) void*)g,
      (__attribute__((address_space(3))) void*)l, 16, 0, 0);
}
// swizzled LDS fragment read: tile [R rows][64 u16], phys seg = kseg ^ (row&7)
__device__ __forceinline__ bf16x8 ldsf(const u16* s, int row, int kseg) {
  return *(const bf16x8*)(s + (row << 6) + ((kseg ^ (row & 7)) << 3));
}

// ---------------- RMSNorm -> split bf16 (hi/lo) + fused ve-gates ----------------
// blocks >= NTOK convert QKVO weights to split bf16 (one 8-float chunk per thread).
__global__ __launch_bounds__(256) void rmsnorm_split_k(const float* __restrict__ in,
                                                       u16* __restrict__ hio,
                                                       u16* __restrict__ loo,
                                                       const float* __restrict__ gW,
                                                       float* __restrict__ gates,
                                                       const float* __restrict__ p0,
                                                       const float* __restrict__ p1,
                                                       const float* __restrict__ p2,
                                                       const float* __restrict__ p3,
                                                       u16* __restrict__ h0, u16* __restrict__ l0,
                                                       u16* __restrict__ h1, u16* __restrict__ l1,
                                                       u16* __restrict__ h2, u16* __restrict__ l2,
                                                       u16* __restrict__ h3, u16* __restrict__ l3) {
  const int bid = blockIdx.x;
  const int t = threadIdx.x;
  if (bid >= NTOK) {
    int chunk = (bid - NTOK) * 256 + t;
    const float* inw; u16* ho; u16* lo2; int loc;
    if (chunk < 131072)      { inw = p0; ho = h0; lo2 = l0; loc = chunk; }
    else if (chunk < 163840) { inw = p1; ho = h1; lo2 = l1; loc = chunk - 131072; }
    else if (chunk < 196608) { inw = p2; ho = h2; lo2 = l2; loc = chunk - 163840; }
    else                     { inw = p3; ho = h3; lo2 = l3; loc = chunk - 196608; }
    size_t i = (size_t)loc * 8;
    float v[8];
    *(float4*)v = *(const float4*)(inw + i);
    *(float4*)(v + 4) = *(const float4*)(inw + i + 4);
    u16 hh[8], ll[8];
#pragma unroll
    for (int j = 0; j < 8; ++j) {
      hh[j] = f2b(v[j]);
      ll[j] = f2b(v[j] - b2f(hh[j]));
    }
    *(bf16x8*)(ho + i) = *(bf16x8*)hh;
    *(bf16x8*)(lo2 + i) = *(bf16x8*)ll;
    return;
  }
  const int rowi = bid;
  float4 v = ((const float4*)(in + (size_t)rowi * CC))[t];
  float ss = v.x * v.x + v.y * v.y + v.z * v.z + v.w * v.w;
#pragma unroll
  for (int off = 32; off; off >>= 1) ss += __shfl_down(ss, off, 64);
  __shared__ float red[4];
  __shared__ float hshare[32];
  if ((t & 63) == 0) red[t >> 6] = ss;
  __syncthreads();
  float tot = red[0] + red[1] + red[2] + red[3];
  float sc = rsqrtf(tot * (1.0f / CC) + EPSF);
  float o[4] = {v.x * sc, v.y * sc, v.z * sc, v.w * sc};
  u16 h[4], l[4];
#pragma unroll
  for (int j = 0; j < 4; ++j) {
    h[j] = f2b(o[j]);
    l[j] = f2b(o[j] - b2f(h[j]));
  }
  *(u16x4*)(hio + (size_t)rowi * CC + t * 4) = *(u16x4*)h;
  *(u16x4*)(loo + (size_t)rowi * CC + t * 4) = *(u16x4*)l;
  if (t < 8) *(float4*)&hshare[t << 2] = *(float4*)o;
  __syncthreads();
  if (t < 4) {
    const float* gw = gW + (t << 5);
    float dot = 0.f;
#pragma unroll
    for (int j = 0; j < 32; ++j) dot += hshare[j] * gw[j];
    gates[(rowi << 2) + t] = 2.f / (1.f + __expf(-dot));
  }
}

// ---------------- RMSNorm(x2) -> bf16 h2 + fp32 router logits ----------------
__global__ __launch_bounds__(256) void rmsnorm_logits_k(const float* __restrict__ in,
                                                        u16* __restrict__ b16o,
                                                        const float* __restrict__ rW,
                                                        float* __restrict__ logits) {
  const int rowi = blockIdx.x;
  const int t = threadIdx.x;
  float4 v = ((const float4*)(in + (size_t)rowi * CC))[t];
  float ss = v.x * v.x + v.y * v.y + v.z * v.z + v.w * v.w;
#pragma unroll
  for (int off = 32; off; off >>= 1) ss += __shfl_down(ss, off, 64);
  __shared__ float red[4];
  __shared__ float red2[8][4];
  if ((t & 63) == 0) red[t >> 6] = ss;
  __syncthreads();
  float tot = red[0] + red[1] + red[2] + red[3];
  float sc = rsqrtf(tot * (1.0f / CC) + EPSF);
  float o[4] = {v.x * sc, v.y * sc, v.z * sc, v.w * sc};
  u16 h[4] = {f2b(o[0]), f2b(o[1]), f2b(o[2]), f2b(o[3])};
  *(u16x4*)(b16o + (size_t)rowi * CC + t * 4) = *(u16x4*)h;
  const float* rwp = rW + (t << 2);
  float part[8];
#pragma unroll
  for (int e = 0; e < 8; ++e) {
    const float* w = rwp + (e << 10);
    part[e] = o[0] * w[0] + o[1] * w[1] + o[2] * w[2] + o[3] * w[3];
  }
  const int wid = t >> 6;
#pragma unroll
  for (int e = 0; e < 8; ++e) {
    float p = part[e];
#pragma unroll
    for (int off = 32; off; off >>= 1) p += __shfl_down(p, off, 64);
    if ((t & 63) == 0) red2[e][wid] = p;
  }
  __syncthreads();
  if (t < 8) logits[rowi * 8 + t] = red2[t][0] + red2[t][1] + red2[t][2] + red2[t][3];
}

// ---------------- bf16 MFMA GEMM: C[M,N] = A[M,K] @ W[N,K]^T ----------------
// 128x64 tile, BK=64, 4 waves of 32rows x 64cols (acc[2][4]). Single-buffer staging.
// MODE:
// 4 gathered A, relu^2 bf16 out (expert fc; e==8 -> shared: identity gather, Wk1 weights)
// 5 gathered rows, w*atomicAdd f32 (expert proj; e==8 -> shared: w=1, Wk1 weights)
// 6 split(3-mfma), f32 x2 = v+addv, also pre-init out ((float*)Cb)
// 11 split fused QKV: N=1536 col-space; Q->rope+rms, K->rope+rms, V->gate (transposed store)
template <int MODE>
__global__ __launch_bounds__(256) void gemm_bf_k(
    const u16* __restrict__ A, const u16* __restrict__ A2,
    const u16* __restrict__ Wt, const u16* __restrict__ W2,
    const u16* __restrict__ Wk1, const u16* __restrict__ Wk2,
    const u16* __restrict__ Wv1, const u16* __restrict__ Wv2,
    float* __restrict__ Cf, u16* __restrict__ Cb,
    u16* __restrict__ Ck, u16* __restrict__ Cv,
    const float* __restrict__ addv, int N, int K,
    const int* __restrict__ offsets, const int* __restrict__ counts,
    const int* __restrict__ tok_idx, const float* __restrict__ tok_w,
    const float* __restrict__ cosb, const float* __restrict__ sinb,
    const float* __restrict__ gates, const float* __restrict__ vein) {
  constexpr bool SPLIT = (MODE == 6 || MODE == 11);
  __shared__ __align__(16) u16 Asw[SPLIT ? 16384 : 8192];
  __shared__ __align__(16) u16 Bsw[SPLIT ? 8192 : 4096];
  const int t = threadIdx.x;
  const int lane = t & 63;
  const int l15 = lane & 15, hi = lane >> 4;
  const int wave = t >> 6;
  const int e = blockIdx.z;
  const int mt = blockIdx.y << 7;
  const int bn = blockIdx.x << 6;
  int base = 0, cnt = 0;
  if (MODE == 4 || MODE == 5) {
    cnt = (e == 8) ? NTOK : counts[e];
    if (mt >= cnt) return;
    base = (e == 8) ? 8192 : offsets[e];
  }
  const int r8 = t >> 3;
  const int ksg = (t & 7) ^ (r8 & 7);  // inverse-swizzled global k-segment
  const u16* asrc[4];
  const u16* bsrc[2];
  const u16* asrc2[4];
  const u16* bsrc2[2];
  // weight selection
  const u16* W1p = Wt;
  if (MODE == 4 || MODE == 5) W1p = (e == 8) ? Wk1 : Wt + ((size_t)e << 20);
  const u16* W2p = W2;
  int wrow = bn;
  if (MODE == 11) {
    if (bn >= 1280)      { W1p = Wv1; W2p = Wv2; wrow = bn - 1280; }
    else if (bn >= 1024) { W1p = Wk1; W2p = Wk2; wrow = bn - 1024; }
  }
#pragma unroll
  for (int g = 0; g < 4; ++g) {
    int rl = (g << 5) + r8;
    int arow;
    if (MODE == 4) {
      int rr = mt + rl; if (rr > cnt - 1) rr = cnt - 1;
      arow = (e == 8) ? rr : tok_idx[base + rr];
    } else if (MODE == 5) {
      int rr = mt + rl; if (rr > cnt - 1) rr = cnt - 1;
      arow = base + rr;
    } else {
      arow = mt + rl;
    }
    size_t ao = (size_t)arow * K + (ksg << 3);
    asrc[g] = A + ao;
    if (SPLIT) asrc2[g] = A2 + ao;
  }
#pragma unroll
  for (int g = 0; g < 2; ++g) {
    size_t bo = (size_t)(wrow + (g << 5) + r8) * K + (ksg << 3);
    bsrc[g] = W1p + bo;
    if (SPLIT) bsrc2[g] = W2p + bo;
  }
  f32x4 acc[2][4] = {};
  const int nkt = K >> 6;
  for (int kt = 0; kt < nkt; ++kt) {
    __syncthreads();
    const int ko = kt << 6;
#pragma unroll
    for (int g = 0; g < 4; ++g) {
      int co = ((g << 8) + t) << 3;
      gload16(asrc[g] + ko, &Asw[co]);
      if (SPLIT) gload16(asrc2[g] + ko, &Asw[8192 + co]);
    }
#pragma unroll
    for (int g = 0; g < 2; ++g) {
      int co = ((g << 8) + t) << 3;
      gload16(bsrc[g] + ko, &Bsw[co]);
      if (SPLIT) gload16(bsrc2[g] + ko, &Bsw[4096 + co]);
    }
    __syncthreads();
#pragma unroll
    for (int kk = 0; kk < 2; ++kk) {
      bf16x8 ah[2], bh[4];
#pragma unroll
      for (int mi = 0; mi < 2; ++mi)
        ah[mi] = ldsf(Asw, (wave << 5) + (mi << 4) + l15, (kk << 2) + hi);
#pragma unroll
      for (int nj = 0; nj < 4; ++nj)
        bh[nj] = ldsf(Bsw, (nj << 4) + l15, (kk << 2) + hi);
#pragma unroll
      for (int mi = 0; mi < 2; ++mi)
#pragma unroll
        for (int nj = 0; nj < 4; ++nj)
          acc[mi][nj] = __builtin_amdgcn_mfma_f32_16x16x32_bf16(ah[mi], bh[nj], acc[mi][nj], 0, 0, 0);
      if (SPLIT) {
        bf16x8 al[2], bl[4];
#pragma unroll
        for (int mi = 0; mi < 2; ++mi)
          al[mi] = ldsf(Asw + 8192, (wave << 5) + (mi << 4) + l15, (kk << 2) + hi);
#pragma unroll
        for (int nj = 0; nj < 4; ++nj)
          bl[nj] = ldsf(Bsw + 4096, (nj << 4) + l15, (kk << 2) + hi);
#pragma unroll
        for (int mi = 0; mi < 2; ++mi)
#pragma unroll
          for (int nj = 0; nj < 4; ++nj) {
            acc[mi][nj] = __builtin_amdgcn_mfma_f32_16x16x32_bf16(ah[mi], bl[nj], acc[mi][nj], 0, 0, 0);
            acc[mi][nj] = __builtin_amdgcn_mfma_f32_16x16x32_bf16(al[mi], bh[nj], acc[mi][nj], 0, 0, 0);
          }
      }
    }
  }
  // ---- epilogues (C/D layout: col=l15, row=hi*4+r; block col span = bn..bn+63) ----
  if (MODE == 11) {
    if (bn < 1280) {
      // rope + per-head rmsnorm (Q or K); block's 64 cols = one head
      u16* outp = (bn < 1024) ? Cb : Ck;
      const int stride = (bn < 1024) ? 1024 : 256;
      const int cbase = (bn < 1024) ? bn : (bn - 1024);
#pragma unroll
      for (int mi = 0; mi < 2; ++mi) {
#pragma unroll
        for (int r = 0; r < 4; ++r) {
          int row = mt + (wave << 5) + (mi << 4) + (hi << 2) + r;
          int tpos = row & (TT - 1);
          const float* cp = cosb + (tpos << 5);
          const float* sp = sinb + (tpos << 5);
          float c0 = cp[l15], s0 = sp[l15];
          float c1 = cp[16 + l15], s1 = sp[16 + l15];
          float a0 = acc[mi][0][r], a1 = acc[mi][1][r];
          float b0 = acc[mi][2][r], b1 = acc[mi][3][r];
          float r00 = a0 * c0 + b0 * s0;
          float r01 = a1 * c1 + b1 * s1;
          float r10 = b0 * c0 - a0 * s0;
          float r11 = b1 * c1 - a1 * s1;
          float ss = r00 * r00 + r01 * r01 + r10 * r10 + r11 * r11;
          ss += __shfl_xor(ss, 1, 64); ss += __shfl_xor(ss, 2, 64);
          ss += __shfl_xor(ss, 4, 64); ss += __shfl_xor(ss, 8, 64);
          float scn = rsqrtf(ss * (1.f / 64.f) + EPSF);
          u16* qp = outp + (size_t)row * stride + cbase;
          qp[l15]      = f2b(r00 * scn);
          qp[16 + l15] = f2b(r01 * scn);
          qp[32 + l15] = f2b(r10 * scn);
          qp[48 + l15] = f2b(r11 * scn);
        }
      }
    } else {
      // V: gate epilogue, store TRANSPOSED: Cv[((b*4+kvh)*64 + d)*2048 + tok_in_b]
      const int cbase = bn - 1280;
      const int kvh = cbase >> 6;
#pragma unroll
      for (int mi = 0; mi < 2; ++mi) {
#pragma unroll
        for (int r = 0; r < 4; ++r) {
          int row = mt + (wave << 5) + (mi << 4) + (hi << 2) + r;
          float g = gates[(row << 2) + kvh];
          const float* vep = vein + ((size_t)row << 8) + cbase;
          size_t vb_base = ((size_t)(((row >> 11) << 2) + kvh) << 17) + (row & (TT - 1));
#pragma unroll
          for (int nj = 0; nj < 4; ++nj) {
            int d = (nj << 4) + l15;
            Cv[vb_base + ((size_t)d << 11)] = f2b(acc[mi][nj][r] + g * vep[d]);
          }
        }
      }
    }
    return;
  }
#pragma unroll
  for (int mi = 0; mi < 2; ++mi) {
#pragma unroll
    for (int r = 0; r < 4; ++r) {
      int rl = (wave << 5) + (mi << 4) + (hi << 2) + r;
      if (MODE == 4 || MODE == 5) {
        int rr = mt + rl;
        if (rr >= cnt) continue;
        if (MODE == 4) {
          size_t ro = (size_t)(base + rr) * N;
#pragma unroll
          for (int nj = 0; nj < 4; ++nj) {
            float v = acc[mi][nj][r];
            v = v > 0.f ? v * v : 0.f;
            Cb[ro + bn + (nj << 4) + l15] = f2b(v);
          }
        } else {
          int tok = (e == 8) ? rr : tok_idx[base + rr];
          float w = (e == 8) ? 1.0f : tok_w[base + rr];
          size_t ro = (size_t)tok * N;
#pragma unroll
          for (int nj = 0; nj < 4; ++nj)
            atomicAdd(&Cf[ro + bn + (nj << 4) + l15], acc[mi][nj][r] * w);
        }
      } else {  // MODE 6
        size_t ro = (size_t)(mt + rl) * N;
        float* outp = (float*)Cb;
#pragma unroll
        for (int nj = 0; nj < 4; ++nj) {
          int col = bn + (nj << 4) + l15;
          float v = acc[mi][nj][r] + addv[ro + col];
          Cf[ro + col] = v;
          outp[ro + col] = v;
        }
      }
    }
  }
}

// ---------------- flash attention, split-K, dbuf K/V staging; idle blocks convert weights ----------------
// FROZEN NUMERICS: max-tracked online softmax, exact op order from rounds 13/15/16 (passing).
// grid = (128 q-frags, 4 kvh, 4 = b*2+seg), 256 threads = 4 waves; wave w = head kvh*4+w.
// The 512 (qf<64, seg=1) blocks convert shared/expert weights (hidden under attn).
__global__ __launch_bounds__(256) void attn_mfma_k(const u16* __restrict__ qb,
                                                   const u16* __restrict__ kb,
                                                   const u16* __restrict__ vbT,
                                                   u16* __restrict__ yh,
                                                   u16* __restrict__ yl,
                                                   const int* __restrict__ wszp,
                                                   float* __restrict__ po,
                                                   float* __restrict__ pml,
                                                   const float* __restrict__ cSfc,
                                                   const float* __restrict__ cSproj,
                                                   const float* __restrict__ cEfc,
                                                   const float* __restrict__ cEproj,
                                                   u16* __restrict__ oSfc,
                                                   u16* __restrict__ oSproj,
                                                   u16* __restrict__ oEfc,
                                                   u16* __restrict__ oEproj) {
  const int z = blockIdx.z;
  const int b = z >> 1, seg = z & 1;
  const int kvh = blockIdx.y;
  const int qf = 127 - (int)blockIdx.x;  // LPT: longest first
  const int t = threadIdx.x;
  if (qf < 64 && seg) {
    // converter block: 4608 chunks of 8 floats each (18 iters x 256 threads)
    const int cid = (((b << 2) + kvh) << 6) + ((int)blockIdx.x - 64);
    int chunk = cid * 4608 + t;
#pragma unroll
    for (int it = 0; it < 18; ++it, chunk += 256) {
      const float* in;
      u16* ou;
      int loc;
      if (chunk < 131072)       { in = cSfc;   ou = oSfc;   loc = chunk; }
      else if (chunk < 262144)  { in = cSproj; ou = oSproj; loc = chunk - 131072; }
      else if (chunk < 1310720) { in = cEfc;   ou = oEfc;   loc = chunk - 262144; }
      else                      { in = cEproj; ou = oEproj; loc = chunk - 1310720; }
      size_t i = (size_t)loc * 8;
      float4 a = *(const float4*)(in + i);
      float4 bb = *(const float4*)(in + i + 4);
      u16 r[8] = {f2b(a.x), f2b(a.y), f2b(a.z), f2b(a.w),
                  f2b(bb.x), f2b(bb.y), f2b(bb.z), f2b(bb.w)};
      *(bf16x8*)(ou + i) = *(bf16x8*)r;
    }
    return;
  }
  const int Wn = *wszp;
  const int lane = t & 63, wave = t >> 6;
  const int h = (kvh << 2) + wave;
  const int l15 = lane & 15, hi = lane >> 4;

  __shared__ __align__(16) u16 Klds[2 * 4096];    // dbuf swizzled [key][d]
  __shared__ __align__(16) u16 Vt[2 * 4096];      // dbuf swizzled [d][key]
  __shared__ __align__(16) u16 Plds[4][16 * 64];  // per-wave swizzled [qrow][key]

  const int qrow0 = qf << 4;
  const int diag = qrow0 >> 6;
  int lo = qrow0 - Wn + 1;
  const int kt0f = lo > 0 ? (lo >> 6) : 0;
  int kt0 = kt0f, ktend = diag;
  if (qf >= 64) {
    int nt = diag - kt0f + 1;
    int mid = kt0f + (nt >> 1);
    if (seg == 0) ktend = mid - 1; else kt0 = mid;
  }

  bf16x8 aQ0, aQ1;
  {
    const u16* qp = qb + ((size_t)((b << 11) + qrow0 + l15) << 10) + (h << 6) + (hi << 3);
    aQ0 = *(const bf16x8*)qp;
    aQ1 = *(const bf16x8*)(qp + 32);
  }
  f32x4 o[4] = {};
  float mrow[4] = {-INFINITY, -INFINITY, -INFINITY, -INFINITY};
  float lrow[4] = {0.f, 0.f, 0.f, 0.f};

  const int kr0 = t >> 3, kc = t & 7;  // staging coords (row 0..31, 8-elem col chunk)
  const u16* vbase = vbT + ((size_t)((b << 2) + kvh) << 17);

  // prologue: stage kt0 into buf 0
#pragma unroll
  for (int i = 0; i < 2; ++i) {
    int row = kr0 + (i << 5);
    int scol = (kc ^ (row & 7)) << 3;
    gload16(kb + ((size_t)((b << 11) + (kt0 << 6) + row) << 8) + (kvh << 6) + scol,
            &Klds[(t << 3) + (i << 11)]);
    gload16(vbase + ((size_t)row << 11) + (kt0 << 6) + scol,
            &Vt[(t << 3) + (i << 11)]);
  }
  int cur = 0;

  for (int kt = kt0; kt <= ktend; ++kt) {
    __syncthreads();  // buf[cur] loads drained; prior reads of buf[cur^1] retired
    if (kt + 1 <= ktend) {
      const int nb = (cur ^ 1) << 12;
#pragma unroll
      for (int i = 0; i < 2; ++i) {
        int row = kr0 + (i << 5);
        int scol = (kc ^ (row & 7)) << 3;
        gload16(kb + ((size_t)((b << 11) + ((kt + 1) << 6) + row) << 8) + (kvh << 6) + scol,
                &Klds[nb + (t << 3) + (i << 11)]);
        gload16(vbase + ((size_t)row << 11) + ((kt + 1) << 6) + scol,
                &Vt[nb + (t << 3) + (i << 11)]);
      }
    }
    const u16* Kb = Klds + (cur << 12);
    const u16* Vb = Vt + (cur << 12);

    // QK^T (setprio around MFMA cluster)
    float sv[4][4];
    __builtin_amdgcn_s_setprio(1);
#pragma unroll
    for (int kb4 = 0; kb4 < 4; ++kb4) {
      f32x4 S = {0.f, 0.f, 0.f, 0.f};
      bf16x8 B0 = ldsf(Kb, (kb4 << 4) + l15, hi);
      bf16x8 B1 = ldsf(Kb, (kb4 << 4) + l15, 4 + hi);
      S = __builtin_amdgcn_mfma_f32_16x16x32_bf16(aQ0, B0, S, 0, 0, 0);
      S = __builtin_amdgcn_mfma_f32_16x16x32_bf16(aQ1, B1, S, 0, 0, 0);
#pragma unroll
      for (int r = 0; r < 4; ++r) sv[kb4][r] = S[r] * 0.125f;
    }
    __builtin_amdgcn_s_setprio(0);
    // masking only on diagonal / window-edge tiles (wave-uniform branch)
    if (kt == diag || kt == kt0f) {
#pragma unroll
      for (int kb4 = 0; kb4 < 4; ++kb4) {
        int key = (kt << 6) + (kb4 << 4) + l15;
#pragma unroll
        for (int r = 0; r < 4; ++r) {
          int qg = qrow0 + (hi << 2) + r;
          if (!(key <= qg && key > qg - Wn)) sv[kb4][r] = -INFINITY;
        }
      }
    }

    // online softmax (4 independent chains), guard-free exp
    float scl[4], pv[4][4];
#pragma unroll
    for (int r = 0; r < 4; ++r) {
      float mt2 = fmaxf(fmaxf(sv[0][r], sv[1][r]), fmaxf(sv[2][r], sv[3][r]));
      mt2 = fmaxf(mt2, __shfl_xor(mt2, 1, 64));
      mt2 = fmaxf(mt2, __shfl_xor(mt2, 2, 64));
      mt2 = fmaxf(mt2, __shfl_xor(mt2, 4, 64));
      mt2 = fmaxf(mt2, __shfl_xor(mt2, 8, 64));
      float mn = fmaxf(fmaxf(mrow[r], mt2), -1e30f);
      float sc = __expf(mrow[r] - mn);
      float rs = 0.f;
#pragma unroll
      for (int kb4 = 0; kb4 < 4; ++kb4) {
        float p = __expf(sv[kb4][r] - mn);
        pv[kb4][r] = p;
        rs += p;
      }
      rs += __shfl_xor(rs, 1, 64);
      rs += __shfl_xor(rs, 2, 64);
      rs += __shfl_xor(rs, 4, 64);
      rs += __shfl_xor(rs, 8, 64);
      mrow[r] = mn;
      lrow[r] = lrow[r] * sc + rs;
      scl[r] = sc;
    }

    // P -> wave-local swizzled LDS
#pragma unroll
    for (int kb4 = 0; kb4 < 4; ++kb4)
#pragma unroll
      for (int r = 0; r < 4; ++r) {
        int row16 = (hi << 2) + r;
        int seg2 = (kb4 << 1) + (l15 >> 3);
        Plds[wave][(row16 << 6) + ((seg2 ^ (row16 & 7)) << 3) + (l15 & 7)] = f2b(pv[kb4][r]);
      }
    // rescale O
#pragma unroll
    for (int df = 0; df < 4; ++df) {
      f32x4 t4 = o[df];
      t4[0] *= scl[0]; t4[1] *= scl[1]; t4[2] *= scl[2]; t4[3] *= scl[3];
      o[df] = t4;
    }
    // PV (setprio around MFMA cluster)
    __builtin_amdgcn_s_setprio(1);
#pragma unroll
    for (int ks = 0; ks < 2; ++ks) {
      bf16x8 Ap = ldsf(Plds[wave], l15, (ks << 2) + hi);
#pragma unroll
      for (int df = 0; df < 4; ++df) {
        bf16x8 Bv = ldsf(Vb, (df << 4) + l15, (ks << 2) + hi);
        o[df] = __builtin_amdgcn_mfma_f32_16x16x32_bf16(Ap, Bv, o[df], 0, 0, 0);
      }
    }
    __builtin_amdgcn_s_setprio(0);
    cur ^= 1;
  }

  if (qf < 64) {
    float inv[4];
#pragma unroll
    for (int r = 0; r < 4; ++r) inv[r] = lrow[r] > 0.f ? 1.f / lrow[r] : 0.f;
#pragma unroll
    for (int r = 0; r < 4; ++r) {
      size_t rbase = ((size_t)((b << 11) + qrow0 + (hi << 2) + r) << 10) + (h << 6) + l15;
#pragma unroll
      for (int df = 0; df < 4; ++df) {
        float fo = o[df][r] * inv[r];
        u16 hv = f2b(fo);
        yh[rbase + (df << 4)] = hv;
        yl[rbase + (df << 4)] = f2b(fo - b2f(hv));
      }
    }
  } else {
    const int sidx = (b << 1) + seg;
    const int prow0 = qrow0 - 1024;
#pragma unroll
    for (int r = 0; r < 4; ++r) {
      size_t pbase = ((size_t)(sidx * 1024 + prow0 + (hi << 2) + r) << 10) + (h << 6) + l15;
#pragma unroll
      for (int df = 0; df < 4; ++df) po[pbase + (df << 4)] = o[df][r];
    }
    if (l15 == 0) {
#pragma unroll
      for (int r = 0; r < 4; ++r) {
        size_t mb = ((size_t)(sidx * 1024 + prow0 + (hi << 2) + r) << 5) + (h << 1);
        pml[mb] = mrow[r];
        pml[mb + 1] = lrow[r];
      }
    }
  }
}

// ---------------- combine split-K partials -> y (max-tracked merge) ----------------
__global__ __launch_bounds__(256) void combine_k(const float* __restrict__ po,
                                                 const float* __restrict__ pml,
                                                 u16* __restrict__ yh,
                                                 u16* __restrict__ yl) {
  const int prow = blockIdx.x, b = blockIdx.y;
  const int t = threadIdx.x;
  const int h = t >> 4, d0 = (t & 15) << 2;
  const int s0 = b << 1, s1 = s0 + 1;
  size_t i0 = ((size_t)(s0 * 1024 + prow) << 5) + (h << 1);
  size_t i1 = ((size_t)(s1 * 1024 + prow) << 5) + (h << 1);
  float m0 = pml[i0], l0 = pml[i0 + 1];
  float m1 = pml[i1], l1 = pml[i1 + 1];
  float m = fmaxf(m0, m1);
  float sc0 = __expf(m0 - m), sc1 = __expf(m1 - m);
  float l = l0 * sc0 + l1 * sc1;
  float inv = l > 0.f ? 1.f / l : 0.f;
  size_t o0 = ((size_t)(s0 * 1024 + prow) << 10) + (h << 6) + d0;
  size_t o1 = ((size_t)(s1 * 1024 + prow) << 10) + (h << 6) + d0;
  float4 a = *(const float4*)&po[o0];
  float4 c = *(const float4*)&po[o1];
  float y0 = (a.x * sc0 + c.x * sc1) * inv;
  float y1 = (a.y * sc0 + c.y * sc1) * inv;
  float y2 = (a.z * sc0 + c.z * sc1) * inv;
  float y3 = (a.w * sc0 + c.w * sc1) * inv;
  u16 hv[4] = {f2b(y0), f2b(y1), f2b(y2), f2b(y3)};
  u16 lv[4] = {f2b(y0 - b2f(hv[0])), f2b(y1 - b2f(hv[1])),
               f2b(y2 - b2f(hv[2])), f2b(y3 - b2f(hv[3]))};
  size_t rbase = ((size_t)((b << 11) + 1024 + prow) << 10) + (h << 6) + d0;
  *(u16x4*)(yh + rbase) = *(u16x4*)hv;
  *(u16x4*)(yl + rbase) = *(u16x4*)lv;
}

// ---------------- top-2 router from precomputed logits ----------------
__global__ __launch_bounds__(256) void topk_k(const float* __restrict__ logits,
                                              const float* __restrict__ bias,
                                              int* __restrict__ topi,
                                              float* __restrict__ topw,
                                              int* __restrict__ counts) {
  int n = blockIdx.x * 256 + threadIdx.x;
  if (n >= NTOK) return;
  float sc[8], sel[8];
#pragma unroll
  for (int e2 = 0; e2 < 8; ++e2) {
    float sg = 1.f / (1.f + __expf(-logits[n * 8 + e2]));
    sc[e2] = sg;
    sel[e2] = sg + bias[e2];
  }
  int i1 = 0; float b1 = sel[0];
#pragma unroll
  for (int j = 1; j < 8; ++j) if (sel[j] > b1) { b1 = sel[j]; i1 = j; }
  int i2 = -1; float b2 = -INFINITY;
#pragma unroll
  for (int j = 0; j < 8; ++j) if (j != i1 && sel[j] > b2) { b2 = sel[j]; i2 = j; }
  float w1 = sc[i1], w2 = sc[i2];
  float invs = 1.f / (w1 + w2 + 1e-20f);
  topi[n * 2] = i1; topi[n * 2 + 1] = i2;
  topw[n * 2] = w1 * invs; topw[n * 2 + 1] = w2 * invs;
  atomicAdd(&counts[i1], 1);
  atomicAdd(&counts[i2], 1);
}

__global__ void scan_k(const int* __restrict__ counts, int* __restrict__ offsets) {
  if (threadIdx.x == 0 && blockIdx.x == 0) {
    int s = 0;
    for (int e2 = 0; e2 < 8; ++e2) { offsets[e2] = s; s += counts[e2]; }
    offsets[8] = s;
  }
}

__global__ __launch_bounds__(256) void scatter_k(const int* __restrict__ topi,
                                                 const float* __restrict__ topw,
                                                 const int* __restrict__ offsets,
                                                 int* __restrict__ counts2,
                                                 int* __restrict__ tok_idx,
                                                 float* __restrict__ tok_w) {
  int n = blockIdx.x * 256 + threadIdx.x;
  if (n >= NTOK) return;
  for (int kk = 0; kk < 2; ++kk) {
    int e2 = topi[n * 2 + kk];
    int slot = atomicAdd(&counts2[e2], 1);
    int p = offsets[e2] + slot;
    tok_idx[p] = n;
    tok_w[p] = topw[n * 2 + kk];
  }
}

extern "C" void kernel_launch(void* const* d_in, const int* in_sizes, int n_in,
                              void* d_out, int out_size, void* d_ws, size_t ws_size,
                              hipStream_t stream) {
  const float* x = (const float*)d_in[0];
  const float* ve = (const float*)d_in[1];
  const float* cosb = (const float*)d_in[2];
  const float* sinb = (const float*)d_in[3];
  const float* Wq = (const float*)d_in[4];
  const float* Wk = (const float*)d_in[5];
  const float* Wv = (const float*)d_in[6];
  const float* Wo = (const float*)d_in[7];
  const float* gW = (const float*)d_in[8];
  const float* routerW = (const float*)d_in[9];
  const float* bias = (const float*)d_in[10];
  const float* Wsfc = (const float*)d_in[11];
  const float* Wsproj = (const float*)d_in[12];
  const float* Wefc = (const float*)d_in[13];
  const float* Weproj = (const float*)d_in[14];
  const int* wsz = (const int*)d_in[15];
  float* out = (float*)d_out;
  char* WS = (char*)d_ws;

  // ---- workspace layout (byte offsets), peak ~91 MiB ----
  u16* Wefc_b   = (u16*)(WS + 0);          // 16 MiB
  u16* Weproj_b = (u16*)(WS + 16777216);   // 16 MiB
  u16* Wsfc_b   = (u16*)(WS + 33554432);   // 2 MiB
  u16* Wsproj_b = (u16*)(WS + 35651584);   // 2 MiB
  u16* Wq_hi    = (u16*)(WS + 37748736);   // 2 MiB
  u16* Wq_lo    = (u16*)(WS + 39845888);   // 2 MiB
  u16* Wk_hi    = (u16*)(WS + 41943040);   // 0.5 MiB
  u16* Wk_lo    = (u16*)(WS + 42467328);   // 0.5 MiB
  u16* Wv_hi    = (u16*)(WS + 42991616);   // 0.5 MiB
  u16* Wv_lo    = (u16*)(WS + 43515904);   // 0.5 MiB
  u16* Wo_hi    = (u16*)(WS + 44040192);   // 2 MiB
  u16* Wo_lo    = (u16*)(WS + 46137344);   // 2 MiB
  u16* h_hi     = (u16*)(WS + 48234496);   // 8 MiB [dead after QKV]
  u16* h_lo     = (u16*)(WS + 56623104);   // 8 MiB [dead after QKV]
  u16* qb       = (u16*)(WS + 65011712);   // 8 MiB [dead after attn]
  u16* kb       = (u16*)(WS + 73400320);   // 2 MiB [dead after attn]
  u16* vb       = (u16*)(WS + 75497472);   // 2 MiB [dead after attn] (transposed layout)
  u16* y_hi     = (u16*)(WS + 77594624);   // 8 MiB [dead after Wo gemm]
  u16* y_lo     = (u16*)(WS + 85983232);   // 8 MiB [dead after Wo gemm]
  float* po     = (float*)(WS + 48234496); // 16 MiB over h_hi+h_lo [attn partials; dead after combine]
  float* x2     = (float*)(WS + 48234496); // 16 MiB over po [written post-combine, dead post-logits]
  u16* h2_b     = (u16*)(WS + 85983232);   // 8 MiB over y_lo [written post-Wo]
  u16* he_b     = (u16*)(WS + 48234496);   // 24 MiB over x2+qb [written post-logits], 12288 rows
  float* gates  = (float*)(WS + 94371840); // 64 KiB
  float* logits = (float*)(WS + 94437376); // 128 KiB
  int* meta     = (int*)(WS + 94568448);
  int* counts   = meta;
  int* counts2  = meta + 8;
  int* offsets  = meta + 16;
  int* topi     = meta + 32;
  float* topw   = (float*)(meta + 8224);
  int* tok_idx  = meta + 16416;
  float* tok_w  = (float*)(meta + 24608);
  float* pml    = (float*)(WS + 94703616); // 512 KiB attn partial m/l

  hipMemsetAsync(counts, 0, 16 * sizeof(int), stream);

  // h = rmsnorm(x) split + fused gates; extra 1280 blocks convert QKVO weights (split)
  rmsnorm_split_k<<<NTOK + 1280, 256, 0, stream>>>(x, h_hi, h_lo, gW, gates,
      Wq, Wk, Wv, Wo,
      Wq_hi, Wq_lo, Wk_hi, Wk_lo, Wv_hi, Wv_lo, Wo_hi, Wo_lo);
  // fused QKV split gemm (N=1536, 128x64 tiles) with per-head epilogues (V stored transposed)
  gemm_bf_k<11><<<dim3(24, 32), 256, 0, stream>>>(
      h_hi, h_lo, Wq_hi, Wq_lo, Wk_hi, Wk_lo, Wv_hi, Wv_lo,
      nullptr, qb, kb, vb, nullptr, 1536, 1024,
      nullptr, nullptr, nullptr, nullptr, cosb, sinb, gates, ve);
  // attention (split-K for rows >= 1024) -> y + partials; idle blocks convert expert weights
  attn_mfma_k<<<dim3(128, 4, 4), 256, 0, stream>>>(qb, kb, vb, y_hi, y_lo, wsz, po, pml,
      Wsfc, Wsproj, Wefc, Weproj, Wsfc_b, Wsproj_b, Wefc_b, Weproj_b);
  combine_k<<<dim3(1024, 2), 256, 0, stream>>>(po, pml, y_hi, y_lo);
  // x2 = x + y @ Wo^T (split, 128x64 tiles); also pre-init out = x2
  gemm_bf_k<6><<<dim3(16, 32), 256, 0, stream>>>(
      y_hi, y_lo, Wo_hi, Wo_lo, nullptr, nullptr, nullptr, nullptr,
      x2, (u16*)out, nullptr, nullptr, x, 1024, 1024,
      nullptr, nullptr, nullptr, nullptr, nullptr, nullptr, nullptr, nullptr);
  // h2 = rmsnorm(x2) -> bf16 + fp32 router logits
  rmsnorm_logits_k<<<NTOK, 256, 0, stream>>>(x2, h2_b, routerW, logits);
  // router + bucketing
  topk_k<<<16, 256, 0, stream>>>(logits, bias, topi, topw, counts);
  scan_k<<<1, 64, 0, stream>>>(counts, offsets);
  scatter_k<<<16, 256, 0, stream>>>(topi, topw, offsets, counts2, tok_idx, tok_w);
  // experts (z=8 routed + z==8 shared), 128x64 tiles, fc then proj (atomicAdd into out)
  gemm_bf_k<4><<<dim3(16, 32, 9), 256, 0, stream>>>(
      h2_b, nullptr, Wefc_b, nullptr, Wsfc_b, nullptr, nullptr, nullptr,
      nullptr, he_b, nullptr, nullptr, nullptr, 1024, 1024,
      offsets, counts, tok_idx, nullptr, nullptr, nullptr, nullptr, nullptr);
  gemm_bf_k<5><<<dim3(16, 32, 9), 256, 0, stream>>>(
      he_b, nullptr, Weproj_b, nullptr, Wsproj_b, nullptr, nullptr, nullptr,
      out, nullptr, nullptr, nullptr, nullptr, 1024, 1024,
      offsets, counts, tok_idx, tok_w, nullptr, nullptr, nullptr, nullptr);
}

// Round 19
// 320.425 us; speedup vs baseline: 1.2345x; 1.2136x over previous
//
#include <hip/hip_runtime.h>

// Problem constants
#define TT 2048
#define CC 1024
#define NTOK 4096
#define EPSF 1.1920929e-07f

typedef unsigned short u16;
typedef short bf16x8 __attribute__((ext_vector_type(8)));
typedef u16 u16x4 __attribute__((ext_vector_type(4)));
typedef float f32x4 __attribute__((ext_vector_type(4)));

__device__ __forceinline__ u16 f2b(float f) {
  union { float f; unsigned u; } v; v.f = f;
  unsigned r = v.u + 0x7FFFu + ((v.u >> 16) & 1u);
  return (u16)(r >> 16);
}
__device__ __forceinline__ float b2f(u16 u) {
  union { unsigned u; float f; } v; v.u = ((unsigned)u) << 16;
  return v.f;
}
__device__ __forceinline__ void gload16(const u16* g, u16* l) {
  __builtin_amdgcn_global_load_lds(
      (const __attribute__((address_space(1))) void*)g,
      (__attribute__((address_space(3))) void*)l, 16, 0, 0);
}
// swizzled LDS fragment read: tile [R rows][64 u16], phys seg = kseg ^ (row&7)
__device__ __forceinline__ bf16x8 ldsf(const u16* s, int row, int kseg) {
  return *(const bf16x8*)(s + (row << 6) + ((kseg ^ (row & 7)) << 3));
}

// ---------------- RMSNorm -> split bf16 (hi/lo) + fused ve-gates ----------------
// blocks >= NTOK convert QKVO weights to split bf16 (one 8-float chunk per thread).
__global__ __launch_bounds__(256) void rmsnorm_split_k(const float* __restrict__ in,
                                                       u16* __restrict__ hio,
                                                       u16* __restrict__ loo,
                                                       const float* __restrict__ gW,
                                                       float* __restrict__ gates,
                                                       const float* __restrict__ p0,
                                                       const float* __restrict__ p1,
                                                       const float* __restrict__ p2,
                                                       const float* __restrict__ p3,
                                                       u16* __restrict__ h0, u16* __restrict__ l0,
                                                       u16* __restrict__ h1, u16* __restrict__ l1,
                                                       u16* __restrict__ h2, u16* __restrict__ l2,
                                                       u16* __restrict__ h3, u16* __restrict__ l3) {
  const int bid = blockIdx.x;
  const int t = threadIdx.x;
  if (bid >= NTOK) {
    int chunk = (bid - NTOK) * 256 + t;
    const float* inw; u16* ho; u16* lo2; int loc;
    if (chunk < 131072)      { inw = p0; ho = h0; lo2 = l0; loc = chunk; }
    else if (chunk < 163840) { inw = p1; ho = h1; lo2 = l1; loc = chunk - 131072; }
    else if (chunk < 196608) { inw = p2; ho = h2; lo2 = l2; loc = chunk - 163840; }
    else                     { inw = p3; ho = h3; lo2 = l3; loc = chunk - 196608; }
    size_t i = (size_t)loc * 8;
    float v[8];
    *(float4*)v = *(const float4*)(inw + i);
    *(float4*)(v + 4) = *(const float4*)(inw + i + 4);
    u16 hh[8], ll[8];
#pragma unroll
    for (int j = 0; j < 8; ++j) {
      hh[j] = f2b(v[j]);
      ll[j] = f2b(v[j] - b2f(hh[j]));
    }
    *(bf16x8*)(ho + i) = *(bf16x8*)hh;
    *(bf16x8*)(lo2 + i) = *(bf16x8*)ll;
    return;
  }
  const int rowi = bid;
  float4 v = ((const float4*)(in + (size_t)rowi * CC))[t];
  float ss = v.x * v.x + v.y * v.y + v.z * v.z + v.w * v.w;
#pragma unroll
  for (int off = 32; off; off >>= 1) ss += __shfl_down(ss, off, 64);
  __shared__ float red[4];
  __shared__ float hshare[32];
  if ((t & 63) == 0) red[t >> 6] = ss;
  __syncthreads();
  float tot = red[0] + red[1] + red[2] + red[3];
  float sc = rsqrtf(tot * (1.0f / CC) + EPSF);
  float o[4] = {v.x * sc, v.y * sc, v.z * sc, v.w * sc};
  u16 h[4], l[4];
#pragma unroll
  for (int j = 0; j < 4; ++j) {
    h[j] = f2b(o[j]);
    l[j] = f2b(o[j] - b2f(h[j]));
  }
  *(u16x4*)(hio + (size_t)rowi * CC + t * 4) = *(u16x4*)h;
  *(u16x4*)(loo + (size_t)rowi * CC + t * 4) = *(u16x4*)l;
  if (t < 8) *(float4*)&hshare[t << 2] = *(float4*)o;
  __syncthreads();
  if (t < 4) {
    const float* gw = gW + (t << 5);
    float dot = 0.f;
#pragma unroll
    for (int j = 0; j < 32; ++j) dot += hshare[j] * gw[j];
    gates[(rowi << 2) + t] = 2.f / (1.f + __expf(-dot));
  }
}

// ---------------- RMSNorm(x2) -> bf16 h2 + fp32 router logits ----------------
__global__ __launch_bounds__(256) void rmsnorm_logits_k(const float* __restrict__ in,
                                                        u16* __restrict__ b16o,
                                                        const float* __restrict__ rW,
                                                        float* __restrict__ logits) {
  const int rowi = blockIdx.x;
  const int t = threadIdx.x;
  float4 v = ((const float4*)(in + (size_t)rowi * CC))[t];
  float ss = v.x * v.x + v.y * v.y + v.z * v.z + v.w * v.w;
#pragma unroll
  for (int off = 32; off; off >>= 1) ss += __shfl_down(ss, off, 64);
  __shared__ float red[4];
  __shared__ float red2[8][4];
  if ((t & 63) == 0) red[t >> 6] = ss;
  __syncthreads();
  float tot = red[0] + red[1] + red[2] + red[3];
  float sc = rsqrtf(tot * (1.0f / CC) + EPSF);
  float o[4] = {v.x * sc, v.y * sc, v.z * sc, v.w * sc};
  u16 h[4] = {f2b(o[0]), f2b(o[1]), f2b(o[2]), f2b(o[3])};
  *(u16x4*)(b16o + (size_t)rowi * CC + t * 4) = *(u16x4*)h;
  const float* rwp = rW + (t << 2);
  float part[8];
#pragma unroll
  for (int e = 0; e < 8; ++e) {
    const float* w = rwp + (e << 10);
    part[e] = o[0] * w[0] + o[1] * w[1] + o[2] * w[2] + o[3] * w[3];
  }
  const int wid = t >> 6;
#pragma unroll
  for (int e = 0; e < 8; ++e) {
    float p = part[e];
#pragma unroll
    for (int off = 32; off; off >>= 1) p += __shfl_down(p, off, 64);
    if ((t & 63) == 0) red2[e][wid] = p;
  }
  __syncthreads();
  if (t < 8) logits[rowi * 8 + t] = red2[t][0] + red2[t][1] + red2[t][2] + red2[t][3];
}

// ---------------- bf16 MFMA GEMM: C[M,N] = A[M,K] @ W[N,K]^T ----------------
// 128x64 tile, BK=64, 4 waves of 32rows x 64cols (acc[2][4]). Single-buffer staging.
// MODE:
// 4 gathered A, relu^2 bf16 out (expert fc; ee==8 -> shared: identity gather, Wk1 weights)
// 5 gathered rows, w*atomicAdd f32 (expert proj; ee==8 -> shared: w=1, Wk1 weights)
// 6 split(3-mfma), f32 x2 = v+addv, also pre-init out ((float*)Cb)
// 11 split fused QKV: N=1536 col-space; Q->rope+rms, K->rope+rms, V->gate (transposed store)
// Modes 4/5 remap blockIdx.z so the shared expert (largest stripe) dispatches FIRST.
template <int MODE>
__global__ __launch_bounds__(256) void gemm_bf_k(
    const u16* __restrict__ A, const u16* __restrict__ A2,
    const u16* __restrict__ Wt, const u16* __restrict__ W2,
    const u16* __restrict__ Wk1, const u16* __restrict__ Wk2,
    const u16* __restrict__ Wv1, const u16* __restrict__ Wv2,
    float* __restrict__ Cf, u16* __restrict__ Cb,
    u16* __restrict__ Ck, u16* __restrict__ Cv,
    const float* __restrict__ addv, int N, int K,
    const int* __restrict__ offsets, const int* __restrict__ counts,
    const int* __restrict__ tok_idx, const float* __restrict__ tok_w,
    const float* __restrict__ cosb, const float* __restrict__ sinb,
    const float* __restrict__ gates, const float* __restrict__ vein) {
  constexpr bool SPLIT = (MODE == 6 || MODE == 11);
  __shared__ __align__(16) u16 Asw[SPLIT ? 16384 : 8192];
  __shared__ __align__(16) u16 Bsw[SPLIT ? 8192 : 4096];
  const int t = threadIdx.x;
  const int lane = t & 63;
  const int l15 = lane & 15, hi = lane >> 4;
  const int wave = t >> 6;
  const int e = (MODE == 4 || MODE == 5)
                    ? ((blockIdx.z == 0) ? 8 : (int)blockIdx.z - 1)  // shared expert first
                    : (int)blockIdx.z;
  const int mt = blockIdx.y << 7;
  const int bn = blockIdx.x << 6;
  int base = 0, cnt = 0;
  if (MODE == 4 || MODE == 5) {
    cnt = (e == 8) ? NTOK : counts[e];
    if (mt >= cnt) return;
    base = (e == 8) ? 8192 : offsets[e];
  }
  const int r8 = t >> 3;
  const int ksg = (t & 7) ^ (r8 & 7);  // inverse-swizzled global k-segment
  const u16* asrc[4];
  const u16* bsrc[2];
  const u16* asrc2[4];
  const u16* bsrc2[2];
  // weight selection
  const u16* W1p = Wt;
  if (MODE == 4 || MODE == 5) W1p = (e == 8) ? Wk1 : Wt + ((size_t)e << 20);
  const u16* W2p = W2;
  int wrow = bn;
  if (MODE == 11) {
    if (bn >= 1280)      { W1p = Wv1; W2p = Wv2; wrow = bn - 1280; }
    else if (bn >= 1024) { W1p = Wk1; W2p = Wk2; wrow = bn - 1024; }
  }
#pragma unroll
  for (int g = 0; g < 4; ++g) {
    int rl = (g << 5) + r8;
    int arow;
    if (MODE == 4) {
      int rr = mt + rl; if (rr > cnt - 1) rr = cnt - 1;
      arow = (e == 8) ? rr : tok_idx[base + rr];
    } else if (MODE == 5) {
      int rr = mt + rl; if (rr > cnt - 1) rr = cnt - 1;
      arow = base + rr;
    } else {
      arow = mt + rl;
    }
    size_t ao = (size_t)arow * K + (ksg << 3);
    asrc[g] = A + ao;
    if (SPLIT) asrc2[g] = A2 + ao;
  }
#pragma unroll
  for (int g = 0; g < 2; ++g) {
    size_t bo = (size_t)(wrow + (g << 5) + r8) * K + (ksg << 3);
    bsrc[g] = W1p + bo;
    if (SPLIT) bsrc2[g] = W2p + bo;
  }
  f32x4 acc[2][4] = {};
  const int nkt = K >> 6;
  for (int kt = 0; kt < nkt; ++kt) {
    __syncthreads();
    const int ko = kt << 6;
#pragma unroll
    for (int g = 0; g < 4; ++g) {
      int co = ((g << 8) + t) << 3;
      gload16(asrc[g] + ko, &Asw[co]);
      if (SPLIT) gload16(asrc2[g] + ko, &Asw[8192 + co]);
    }
#pragma unroll
    for (int g = 0; g < 2; ++g) {
      int co = ((g << 8) + t) << 3;
      gload16(bsrc[g] + ko, &Bsw[co]);
      if (SPLIT) gload16(bsrc2[g] + ko, &Bsw[4096 + co]);
    }
    __syncthreads();
#pragma unroll
    for (int kk = 0; kk < 2; ++kk) {
      bf16x8 ah[2], bh[4];
#pragma unroll
      for (int mi = 0; mi < 2; ++mi)
        ah[mi] = ldsf(Asw, (wave << 5) + (mi << 4) + l15, (kk << 2) + hi);
#pragma unroll
      for (int nj = 0; nj < 4; ++nj)
        bh[nj] = ldsf(Bsw, (nj << 4) + l15, (kk << 2) + hi);
#pragma unroll
      for (int mi = 0; mi < 2; ++mi)
#pragma unroll
        for (int nj = 0; nj < 4; ++nj)
          acc[mi][nj] = __builtin_amdgcn_mfma_f32_16x16x32_bf16(ah[mi], bh[nj], acc[mi][nj], 0, 0, 0);
      if (SPLIT) {
        bf16x8 al[2], bl[4];
#pragma unroll
        for (int mi = 0; mi < 2; ++mi)
          al[mi] = ldsf(Asw + 8192, (wave << 5) + (mi << 4) + l15, (kk << 2) + hi);
#pragma unroll
        for (int nj = 0; nj < 4; ++nj)
          bl[nj] = ldsf(Bsw + 4096, (nj << 4) + l15, (kk << 2) + hi);
#pragma unroll
        for (int mi = 0; mi < 2; ++mi)
#pragma unroll
          for (int nj = 0; nj < 4; ++nj) {
            acc[mi][nj] = __builtin_amdgcn_mfma_f32_16x16x32_bf16(ah[mi], bl[nj], acc[mi][nj], 0, 0, 0);
            acc[mi][nj] = __builtin_amdgcn_mfma_f32_16x16x32_bf16(al[mi], bh[nj], acc[mi][nj], 0, 0, 0);
          }
      }
    }
  }
  // ---- epilogues (C/D layout: col=l15, row=hi*4+r; block col span = bn..bn+63) ----
  if (MODE == 11) {
    if (bn < 1280) {
      // rope + per-head rmsnorm (Q or K); block's 64 cols = one head
      u16* outp = (bn < 1024) ? Cb : Ck;
      const int stride = (bn < 1024) ? 1024 : 256;
      const int cbase = (bn < 1024) ? bn : (bn - 1024);
#pragma unroll
      for (int mi = 0; mi < 2; ++mi) {
#pragma unroll
        for (int r = 0; r < 4; ++r) {
          int row = mt + (wave << 5) + (mi << 4) + (hi << 2) + r;
          int tpos = row & (TT - 1);
          const float* cp = cosb + (tpos << 5);
          const float* sp = sinb + (tpos << 5);
          float c0 = cp[l15], s0 = sp[l15];
          float c1 = cp[16 + l15], s1 = sp[16 + l15];
          float a0 = acc[mi][0][r], a1 = acc[mi][1][r];
          float b0 = acc[mi][2][r], b1 = acc[mi][3][r];
          float r00 = a0 * c0 + b0 * s0;
          float r01 = a1 * c1 + b1 * s1;
          float r10 = b0 * c0 - a0 * s0;
          float r11 = b1 * c1 - a1 * s1;
          float ss = r00 * r00 + r01 * r01 + r10 * r10 + r11 * r11;
          ss += __shfl_xor(ss, 1, 64); ss += __shfl_xor(ss, 2, 64);
          ss += __shfl_xor(ss, 4, 64); ss += __shfl_xor(ss, 8, 64);
          float scn = rsqrtf(ss * (1.f / 64.f) + EPSF);
          u16* qp = outp + (size_t)row * stride + cbase;
          qp[l15]      = f2b(r00 * scn);
          qp[16 + l15] = f2b(r01 * scn);
          qp[32 + l15] = f2b(r10 * scn);
          qp[48 + l15] = f2b(r11 * scn);
        }
      }
    } else {
      // V: gate epilogue, store TRANSPOSED: Cv[((b*4+kvh)*64 + d)*2048 + tok_in_b]
      const int cbase = bn - 1280;
      const int kvh = cbase >> 6;
#pragma unroll
      for (int mi = 0; mi < 2; ++mi) {
#pragma unroll
        for (int r = 0; r < 4; ++r) {
          int row = mt + (wave << 5) + (mi << 4) + (hi << 2) + r;
          float g = gates[(row << 2) + kvh];
          const float* vep = vein + ((size_t)row << 8) + cbase;
          size_t vb_base = ((size_t)(((row >> 11) << 2) + kvh) << 17) + (row & (TT - 1));
#pragma unroll
          for (int nj = 0; nj < 4; ++nj) {
            int d = (nj << 4) + l15;
            Cv[vb_base + ((size_t)d << 11)] = f2b(acc[mi][nj][r] + g * vep[d]);
          }
        }
      }
    }
    return;
  }
#pragma unroll
  for (int mi = 0; mi < 2; ++mi) {
#pragma unroll
    for (int r = 0; r < 4; ++r) {
      int rl = (wave << 5) + (mi << 4) + (hi << 2) + r;
      if (MODE == 4 || MODE == 5) {
        int rr = mt + rl;
        if (rr >= cnt) continue;
        if (MODE == 4) {
          size_t ro = (size_t)(base + rr) * N;
#pragma unroll
          for (int nj = 0; nj < 4; ++nj) {
            float v = acc[mi][nj][r];
            v = v > 0.f ? v * v : 0.f;
            Cb[ro + bn + (nj << 4) + l15] = f2b(v);
          }
        } else {
          int tok = (e == 8) ? rr : tok_idx[base + rr];
          float w = (e == 8) ? 1.0f : tok_w[base + rr];
          size_t ro = (size_t)tok * N;
#pragma unroll
          for (int nj = 0; nj < 4; ++nj)
            atomicAdd(&Cf[ro + bn + (nj << 4) + l15], acc[mi][nj][r] * w);
        }
      } else {  // MODE 6
        size_t ro = (size_t)(mt + rl) * N;
        float* outp = (float*)Cb;
#pragma unroll
        for (int nj = 0; nj < 4; ++nj) {
          int col = bn + (nj << 4) + l15;
          float v = acc[mi][nj][r] + addv[ro + col];
          Cf[ro + col] = v;
          outp[ro + col] = v;
        }
      }
    }
  }
}

// ---------------- flash attention, split-K, dbuf K/V staging; idle blocks convert weights ----------------
// FROZEN NUMERICS: max-tracked online softmax, exact op order from rounds 13/15/16/18 (passing).
// grid = (128 q-frags, 4 kvh, 4 = b*2+seg), 256 threads = 4 waves; wave w = head kvh*4+w.
// The 512 (qf<64, seg=1) blocks convert shared/expert weights (hidden under attn).
__global__ __launch_bounds__(256) void attn_mfma_k(const u16* __restrict__ qb,
                                                   const u16* __restrict__ kb,
                                                   const u16* __restrict__ vbT,
                                                   u16* __restrict__ yh,
                                                   u16* __restrict__ yl,
                                                   const int* __restrict__ wszp,
                                                   float* __restrict__ po,
                                                   float* __restrict__ pml,
                                                   const float* __restrict__ cSfc,
                                                   const float* __restrict__ cSproj,
                                                   const float* __restrict__ cEfc,
                                                   const float* __restrict__ cEproj,
                                                   u16* __restrict__ oSfc,
                                                   u16* __restrict__ oSproj,
                                                   u16* __restrict__ oEfc,
                                                   u16* __restrict__ oEproj) {
  const int z = blockIdx.z;
  const int b = z >> 1, seg = z & 1;
  const int kvh = blockIdx.y;
  const int qf = 127 - (int)blockIdx.x;  // LPT: longest first
  const int t = threadIdx.x;
  if (qf < 64 && seg) {
    // converter block: 4608 chunks of 8 floats each (18 iters x 256 threads)
    const int cid = (((b << 2) + kvh) << 6) + ((int)blockIdx.x - 64);
    int chunk = cid * 4608 + t;
#pragma unroll
    for (int it = 0; it < 18; ++it, chunk += 256) {
      const float* in;
      u16* ou;
      int loc;
      if (chunk < 131072)       { in = cSfc;   ou = oSfc;   loc = chunk; }
      else if (chunk < 262144)  { in = cSproj; ou = oSproj; loc = chunk - 131072; }
      else if (chunk < 1310720) { in = cEfc;   ou = oEfc;   loc = chunk - 262144; }
      else                      { in = cEproj; ou = oEproj; loc = chunk - 1310720; }
      size_t i = (size_t)loc * 8;
      float4 a = *(const float4*)(in + i);
      float4 bb = *(const float4*)(in + i + 4);
      u16 r[8] = {f2b(a.x), f2b(a.y), f2b(a.z), f2b(a.w),
                  f2b(bb.x), f2b(bb.y), f2b(bb.z), f2b(bb.w)};
      *(bf16x8*)(ou + i) = *(bf16x8*)r;
    }
    return;
  }
  const int Wn = *wszp;
  const int lane = t & 63, wave = t >> 6;
  const int h = (kvh << 2) + wave;
  const int l15 = lane & 15, hi = lane >> 4;

  __shared__ __align__(16) u16 Klds[2 * 4096];    // dbuf swizzled [key][d]
  __shared__ __align__(16) u16 Vt[2 * 4096];      // dbuf swizzled [d][key]
  __shared__ __align__(16) u16 Plds[4][16 * 64];  // per-wave swizzled [qrow][key]

  const int qrow0 = qf << 4;
  const int diag = qrow0 >> 6;
  int lo = qrow0 - Wn + 1;
  const int kt0f = lo > 0 ? (lo >> 6) : 0;
  int kt0 = kt0f, ktend = diag;
  if (qf >= 64) {
    int nt = diag - kt0f + 1;
    int mid = kt0f + (nt >> 1);
    if (seg == 0) ktend = mid - 1; else kt0 = mid;
  }

  bf16x8 aQ0, aQ1;
  {
    const u16* qp = qb + ((size_t)((b << 11) + qrow0 + l15) << 10) + (h << 6) + (hi << 3);
    aQ0 = *(const bf16x8*)qp;
    aQ1 = *(const bf16x8*)(qp + 32);
  }
  f32x4 o[4] = {};
  float mrow[4] = {-INFINITY, -INFINITY, -INFINITY, -INFINITY};
  float lrow[4] = {0.f, 0.f, 0.f, 0.f};

  const int kr0 = t >> 3, kc = t & 7;  // staging coords (row 0..31, 8-elem col chunk)
  const u16* vbase = vbT + ((size_t)((b << 2) + kvh) << 17);

  // prologue: stage kt0 into buf 0
#pragma unroll
  for (int i = 0; i < 2; ++i) {
    int row = kr0 + (i << 5);
    int scol = (kc ^ (row & 7)) << 3;
    gload16(kb + ((size_t)((b << 11) + (kt0 << 6) + row) << 8) + (kvh << 6) + scol,
            &Klds[(t << 3) + (i << 11)]);
    gload16(vbase + ((size_t)row << 11) + (kt0 << 6) + scol,
            &Vt[(t << 3) + (i << 11)]);
  }
  int cur = 0;

  for (int kt = kt0; kt <= ktend; ++kt) {
    __syncthreads();  // buf[cur] loads drained; prior reads of buf[cur^1] retired
    if (kt + 1 <= ktend) {
      const int nb = (cur ^ 1) << 12;
#pragma unroll
      for (int i = 0; i < 2; ++i) {
        int row = kr0 + (i << 5);
        int scol = (kc ^ (row & 7)) << 3;
        gload16(kb + ((size_t)((b << 11) + ((kt + 1) << 6) + row) << 8) + (kvh << 6) + scol,
                &Klds[nb + (t << 3) + (i << 11)]);
        gload16(vbase + ((size_t)row << 11) + ((kt + 1) << 6) + scol,
                &Vt[nb + (t << 3) + (i << 11)]);
      }
    }
    const u16* Kb = Klds + (cur << 12);
    const u16* Vb = Vt + (cur << 12);

    // QK^T (setprio around MFMA cluster)
    float sv[4][4];
    __builtin_amdgcn_s_setprio(1);
#pragma unroll
    for (int kb4 = 0; kb4 < 4; ++kb4) {
      f32x4 S = {0.f, 0.f, 0.f, 0.f};
      bf16x8 B0 = ldsf(Kb, (kb4 << 4) + l15, hi);
      bf16x8 B1 = ldsf(Kb, (kb4 << 4) + l15, 4 + hi);
      S = __builtin_amdgcn_mfma_f32_16x16x32_bf16(aQ0, B0, S, 0, 0, 0);
      S = __builtin_amdgcn_mfma_f32_16x16x32_bf16(aQ1, B1, S, 0, 0, 0);
#pragma unroll
      for (int r = 0; r < 4; ++r) sv[kb4][r] = S[r] * 0.125f;
    }
    __builtin_amdgcn_s_setprio(0);
    // masking only on diagonal / window-edge tiles (wave-uniform branch)
    if (kt == diag || kt == kt0f) {
#pragma unroll
      for (int kb4 = 0; kb4 < 4; ++kb4) {
        int key = (kt << 6) + (kb4 << 4) + l15;
#pragma unroll
        for (int r = 0; r < 4; ++r) {
          int qg = qrow0 + (hi << 2) + r;
          if (!(key <= qg && key > qg - Wn)) sv[kb4][r] = -INFINITY;
        }
      }
    }

    // online softmax (4 independent chains), guard-free exp
    float scl[4], pv[4][4];
#pragma unroll
    for (int r = 0; r < 4; ++r) {
      float mt2 = fmaxf(fmaxf(sv[0][r], sv[1][r]), fmaxf(sv[2][r], sv[3][r]));
      mt2 = fmaxf(mt2, __shfl_xor(mt2, 1, 64));
      mt2 = fmaxf(mt2, __shfl_xor(mt2, 2, 64));
      mt2 = fmaxf(mt2, __shfl_xor(mt2, 4, 64));
      mt2 = fmaxf(mt2, __shfl_xor(mt2, 8, 64));
      float mn = fmaxf(fmaxf(mrow[r], mt2), -1e30f);
      float sc = __expf(mrow[r] - mn);
      float rs = 0.f;
#pragma unroll
      for (int kb4 = 0; kb4 < 4; ++kb4) {
        float p = __expf(sv[kb4][r] - mn);
        pv[kb4][r] = p;
        rs += p;
      }
      rs += __shfl_xor(rs, 1, 64);
      rs += __shfl_xor(rs, 2, 64);
      rs += __shfl_xor(rs, 4, 64);
      rs += __shfl_xor(rs, 8, 64);
      mrow[r] = mn;
      lrow[r] = lrow[r] * sc + rs;
      scl[r] = sc;
    }

    // P -> wave-local swizzled LDS
#pragma unroll
    for (int kb4 = 0; kb4 < 4; ++kb4)
#pragma unroll
      for (int r = 0; r < 4; ++r) {
        int row16 = (hi << 2) + r;
        int seg2 = (kb4 << 1) + (l15 >> 3);
        Plds[wave][(row16 << 6) + ((seg2 ^ (row16 & 7)) << 3) + (l15 & 7)] = f2b(pv[kb4][r]);
      }
    // rescale O
#pragma unroll
    for (int df = 0; df < 4; ++df) {
      f32x4 t4 = o[df];
      t4[0] *= scl[0]; t4[1] *= scl[1]; t4[2] *= scl[2]; t4[3] *= scl[3];
      o[df] = t4;
    }
    // PV (setprio around MFMA cluster)
    __builtin_amdgcn_s_setprio(1);
#pragma unroll
    for (int ks = 0; ks < 2; ++ks) {
      bf16x8 Ap = ldsf(Plds[wave], l15, (ks << 2) + hi);
#pragma unroll
      for (int df = 0; df < 4; ++df) {
        bf16x8 Bv = ldsf(Vb, (df << 4) + l15, (ks << 2) + hi);
        o[df] = __builtin_amdgcn_mfma_f32_16x16x32_bf16(Ap, Bv, o[df], 0, 0, 0);
      }
    }
    __builtin_amdgcn_s_setprio(0);
    cur ^= 1;
  }

  if (qf < 64) {
    float inv[4];
#pragma unroll
    for (int r = 0; r < 4; ++r) inv[r] = lrow[r] > 0.f ? 1.f / lrow[r] : 0.f;
#pragma unroll
    for (int r = 0; r < 4; ++r) {
      size_t rbase = ((size_t)((b << 11) + qrow0 + (hi << 2) + r) << 10) + (h << 6) + l15;
#pragma unroll
      for (int df = 0; df < 4; ++df) {
        float fo = o[df][r] * inv[r];
        u16 hv = f2b(fo);
        yh[rbase + (df << 4)] = hv;
        yl[rbase + (df << 4)] = f2b(fo - b2f(hv));
      }
    }
  } else {
    const int sidx = (b << 1) + seg;
    const int prow0 = qrow0 - 1024;
#pragma unroll
    for (int r = 0; r < 4; ++r) {
      size_t pbase = ((size_t)(sidx * 1024 + prow0 + (hi << 2) + r) << 10) + (h << 6) + l15;
#pragma unroll
      for (int df = 0; df < 4; ++df) po[pbase + (df << 4)] = o[df][r];
    }
    if (l15 == 0) {
#pragma unroll
      for (int r = 0; r < 4; ++r) {
        size_t mb = ((size_t)(sidx * 1024 + prow0 + (hi << 2) + r) << 5) + (h << 1);
        pml[mb] = mrow[r];
        pml[mb + 1] = lrow[r];
      }
    }
  }
}

// ---------------- combine split-K partials -> y (max-tracked merge) ----------------
__global__ __launch_bounds__(256) void combine_k(const float* __restrict__ po,
                                                 const float* __restrict__ pml,
                                                 u16* __restrict__ yh,
                                                 u16* __restrict__ yl) {
  const int prow = blockIdx.x, b = blockIdx.y;
  const int t = threadIdx.x;
  const int h = t >> 4, d0 = (t & 15) << 2;
  const int s0 = b << 1, s1 = s0 + 1;
  size_t i0 = ((size_t)(s0 * 1024 + prow) << 5) + (h << 1);
  size_t i1 = ((size_t)(s1 * 1024 + prow) << 5) + (h << 1);
  float m0 = pml[i0], l0 = pml[i0 + 1];
  float m1 = pml[i1], l1 = pml[i1 + 1];
  float m = fmaxf(m0, m1);
  float sc0 = __expf(m0 - m), sc1 = __expf(m1 - m);
  float l = l0 * sc0 + l1 * sc1;
  float inv = l > 0.f ? 1.f / l : 0.f;
  size_t o0 = ((size_t)(s0 * 1024 + prow) << 10) + (h << 6) + d0;
  size_t o1 = ((size_t)(s1 * 1024 + prow) << 10) + (h << 6) + d0;
  float4 a = *(const float4*)&po[o0];
  float4 c = *(const float4*)&po[o1];
  float y0 = (a.x * sc0 + c.x * sc1) * inv;
  float y1 = (a.y * sc0 + c.y * sc1) * inv;
  float y2 = (a.z * sc0 + c.z * sc1) * inv;
  float y3 = (a.w * sc0 + c.w * sc1) * inv;
  u16 hv[4] = {f2b(y0), f2b(y1), f2b(y2), f2b(y3)};
  u16 lv[4] = {f2b(y0 - b2f(hv[0])), f2b(y1 - b2f(hv[1])),
               f2b(y2 - b2f(hv[2])), f2b(y3 - b2f(hv[3]))};
  size_t rbase = ((size_t)((b << 11) + 1024 + prow) << 10) + (h << 6) + d0;
  *(u16x4*)(yh + rbase) = *(u16x4*)hv;
  *(u16x4*)(yl + rbase) = *(u16x4*)lv;
}

// ---------------- fused router: top-2 + scan + scatter, one block ----------------
// Top-2 selection math bit-identical to prior topk_k; slot order via LDS atomics
// (order-independent output, same semantics as prior scatter_k).
__global__ __launch_bounds__(256) void router_all_k(const float* __restrict__ logits,
                                                    const float* __restrict__ bias,
                                                    int* __restrict__ counts,
                                                    int* __restrict__ offsets,
                                                    int* __restrict__ tok_idx,
                                                    float* __restrict__ tok_w) {
  __shared__ int cnt[8], off[9], cnt2[8];
  const int t = threadIdx.x;
  if (t < 8) { cnt[t] = 0; cnt2[t] = 0; }
  __syncthreads();
  // phase 1: counts
  for (int k = 0; k < 16; ++k) {
    int n = t * 16 + k;
    float sel[8];
#pragma unroll
    for (int e2 = 0; e2 < 8; ++e2)
      sel[e2] = 1.f / (1.f + __expf(-logits[n * 8 + e2])) + bias[e2];
    int i1 = 0; float b1 = sel[0];
#pragma unroll
    for (int j = 1; j < 8; ++j) if (sel[j] > b1) { b1 = sel[j]; i1 = j; }
    int i2 = -1; float b2 = -INFINITY;
#pragma unroll
    for (int j = 0; j < 8; ++j) if (j != i1 && sel[j] > b2) { b2 = sel[j]; i2 = j; }
    atomicAdd(&cnt[i1], 1);
    atomicAdd(&cnt[i2], 1);
  }
  __syncthreads();
  // phase 2: scan
  if (t == 0) {
    int s = 0;
    for (int e2 = 0; e2 < 8; ++e2) { off[e2] = s; offsets[e2] = s; counts[e2] = cnt[e2]; s += cnt[e2]; }
    off[8] = s; offsets[8] = s;
  }
  __syncthreads();
  // phase 3: scatter (recompute top-2: bit-identical selection)
  for (int k = 0; k < 16; ++k) {
    int n = t * 16 + k;
    float sc[8], sel[8];
#pragma unroll
    for (int e2 = 0; e2 < 8; ++e2) {
      float sg = 1.f / (1.f + __expf(-logits[n * 8 + e2]));
      sc[e2] = sg;
      sel[e2] = sg + bias[e2];
    }
    int i1 = 0; float b1 = sel[0];
#pragma unroll
    for (int j = 1; j < 8; ++j) if (sel[j] > b1) { b1 = sel[j]; i1 = j; }
    int i2 = -1; float b2 = -INFINITY;
#pragma unroll
    for (int j = 0; j < 8; ++j) if (j != i1 && sel[j] > b2) { b2 = sel[j]; i2 = j; }
    float w1 = sc[i1], w2 = sc[i2];
    float invs = 1.f / (w1 + w2 + 1e-20f);
    int s1 = atomicAdd(&cnt2[i1], 1);
    int p1 = off[i1] + s1;
    tok_idx[p1] = n;
    tok_w[p1] = w1 * invs;
    int s2 = atomicAdd(&cnt2[i2], 1);
    int p2 = off[i2] + s2;
    tok_idx[p2] = n;
    tok_w[p2] = w2 * invs;
  }
}

extern "C" void kernel_launch(void* const* d_in, const int* in_sizes, int n_in,
                              void* d_out, int out_size, void* d_ws, size_t ws_size,
                              hipStream_t stream) {
  const float* x = (const float*)d_in[0];
  const float* ve = (const float*)d_in[1];
  const float* cosb = (const float*)d_in[2];
  const float* sinb = (const float*)d_in[3];
  const float* Wq = (const float*)d_in[4];
  const float* Wk = (const float*)d_in[5];
  const float* Wv = (const float*)d_in[6];
  const float* Wo = (const float*)d_in[7];
  const float* gW = (const float*)d_in[8];
  const float* routerW = (const float*)d_in[9];
  const float* bias = (const float*)d_in[10];
  const float* Wsfc = (const float*)d_in[11];
  const float* Wsproj = (const float*)d_in[12];
  const float* Wefc = (const float*)d_in[13];
  const float* Weproj = (const float*)d_in[14];
  const int* wsz = (const int*)d_in[15];
  float* out = (float*)d_out;
  char* WS = (char*)d_ws;

  // ---- workspace layout (byte offsets), peak ~91 MiB ----
  u16* Wefc_b   = (u16*)(WS + 0);          // 16 MiB
  u16* Weproj_b = (u16*)(WS + 16777216);   // 16 MiB
  u16* Wsfc_b   = (u16*)(WS + 33554432);   // 2 MiB
  u16* Wsproj_b = (u16*)(WS + 35651584);   // 2 MiB
  u16* Wq_hi    = (u16*)(WS + 37748736);   // 2 MiB
  u16* Wq_lo    = (u16*)(WS + 39845888);   // 2 MiB
  u16* Wk_hi    = (u16*)(WS + 41943040);   // 0.5 MiB
  u16* Wk_lo    = (u16*)(WS + 42467328);   // 0.5 MiB
  u16* Wv_hi    = (u16*)(WS + 42991616);   // 0.5 MiB
  u16* Wv_lo    = (u16*)(WS + 43515904);   // 0.5 MiB
  u16* Wo_hi    = (u16*)(WS + 44040192);   // 2 MiB
  u16* Wo_lo    = (u16*)(WS + 46137344);   // 2 MiB
  u16* h_hi     = (u16*)(WS + 48234496);   // 8 MiB [dead after QKV]
  u16* h_lo     = (u16*)(WS + 56623104);   // 8 MiB [dead after QKV]
  u16* qb       = (u16*)(WS + 65011712);   // 8 MiB [dead after attn]
  u16* kb       = (u16*)(WS + 73400320);   // 2 MiB [dead after attn]
  u16* vb       = (u16*)(WS + 75497472);   // 2 MiB [dead after attn] (transposed layout)
  u16* y_hi     = (u16*)(WS + 77594624);   // 8 MiB [dead after Wo gemm]
  u16* y_lo     = (u16*)(WS + 85983232);   // 8 MiB [dead after Wo gemm]
  float* po     = (float*)(WS + 48234496); // 16 MiB over h_hi+h_lo [attn partials; dead after combine]
  float* x2     = (float*)(WS + 48234496); // 16 MiB over po [written post-combine, dead post-logits]
  u16* h2_b     = (u16*)(WS + 85983232);   // 8 MiB over y_lo [written post-Wo]
  u16* he_b     = (u16*)(WS + 48234496);   // 24 MiB over x2+qb [written post-logits], 12288 rows
  float* gates  = (float*)(WS + 94371840); // 64 KiB
  float* logits = (float*)(WS + 94437376); // 128 KiB
  int* meta     = (int*)(WS + 94568448);
  int* counts   = meta;
  int* offsets  = meta + 16;
  int* tok_idx  = meta + 16416;
  float* tok_w  = (float*)(meta + 24608);
  float* pml    = (float*)(WS + 94703616); // 512 KiB attn partial m/l

  // h = rmsnorm(x) split + fused gates; extra 1280 blocks convert QKVO weights (split)
  rmsnorm_split_k<<<NTOK + 1280, 256, 0, stream>>>(x, h_hi, h_lo, gW, gates,
      Wq, Wk, Wv, Wo,
      Wq_hi, Wq_lo, Wk_hi, Wk_lo, Wv_hi, Wv_lo, Wo_hi, Wo_lo);
  // fused QKV split gemm (N=1536, 128x64 tiles) with per-head epilogues (V stored transposed)
  gemm_bf_k<11><<<dim3(24, 32), 256, 0, stream>>>(
      h_hi, h_lo, Wq_hi, Wq_lo, Wk_hi, Wk_lo, Wv_hi, Wv_lo,
      nullptr, qb, kb, vb, nullptr, 1536, 1024,
      nullptr, nullptr, nullptr, nullptr, cosb, sinb, gates, ve);
  // attention (split-K for rows >= 1024) -> y + partials; idle blocks convert expert weights
  attn_mfma_k<<<dim3(128, 4, 4), 256, 0, stream>>>(qb, kb, vb, y_hi, y_lo, wsz, po, pml,
      Wsfc, Wsproj, Wefc, Weproj, Wsfc_b, Wsproj_b, Wefc_b, Weproj_b);
  combine_k<<<dim3(1024, 2), 256, 0, stream>>>(po, pml, y_hi, y_lo);
  // x2 = x + y @ Wo^T (split, 128x64 tiles); also pre-init out = x2
  gemm_bf_k<6><<<dim3(16, 32), 256, 0, stream>>>(
      y_hi, y_lo, Wo_hi, Wo_lo, nullptr, nullptr, nullptr, nullptr,
      x2, (u16*)out, nullptr, nullptr, x, 1024, 1024,
      nullptr, nullptr, nullptr, nullptr, nullptr, nullptr, nullptr, nullptr);
  // h2 = rmsnorm(x2) -> bf16 + fp32 router logits
  rmsnorm_logits_k<<<NTOK, 256, 0, stream>>>(x2, h2_b, routerW, logits);
  // fused router (top-2 + scan + scatter), one block
  router_all_k<<<1, 256, 0, stream>>>(logits, bias, counts, offsets, tok_idx, tok_w);
  // experts (z=0 shared first, z=1..8 routed), 128x64 tiles, fc then proj (atomicAdd into out)
  gemm_bf_k<4><<<dim3(16, 32, 9), 256, 0, stream>>>(
      h2_b, nullptr, Wefc_b, nullptr, Wsfc_b, nullptr, nullptr, nullptr,
      nullptr, he_b, nullptr, nullptr, nullptr, 1024, 1024,
      offsets, counts, tok_idx, nullptr, nullptr, nullptr, nullptr, nullptr);
  gemm_bf_k<5><<<dim3(16, 32, 9), 256, 0, stream>>>(
      he_b, nullptr, Weproj_b, nullptr, Wsproj_b, nullptr, nullptr, nullptr,
      out, nullptr, nullptr, nullptr, nullptr, 1024, 1024,
      offsets, counts, tok_idx, tok_w, nullptr, nullptr, nullptr, nullptr);
}

// Round 20
// 319.572 us; speedup vs baseline: 1.2378x; 1.0027x over previous
//
#include <hip/hip_runtime.h>

// Problem constants
#define TT 2048
#define CC 1024
#define NTOK 4096
#define EPSF 1.1920929e-07f

typedef unsigned short u16;
typedef short bf16x8 __attribute__((ext_vector_type(8)));
typedef u16 u16x4 __attribute__((ext_vector_type(4)));
typedef float f32x4 __attribute__((ext_vector_type(4)));

__device__ __forceinline__ u16 f2b(float f) {
  union { float f; unsigned u; } v; v.f = f;
  unsigned r = v.u + 0x7FFFu + ((v.u >> 16) & 1u);
  return (u16)(r >> 16);
}
__device__ __forceinline__ float b2f(u16 u) {
  union { unsigned u; float f; } v; v.u = ((unsigned)u) << 16;
  return v.f;
}
__device__ __forceinline__ void gload16(const u16* g, u16* l) {
  __builtin_amdgcn_global_load_lds(
      (const __attribute__((address_space(1))) void*)g,
      (__attribute__((address_space(3))) void*)l, 16, 0, 0);
}
// swizzled LDS fragment read: tile [R rows][64 u16], phys seg = kseg ^ (row&7)
__device__ __forceinline__ bf16x8 ldsf(const u16* s, int row, int kseg) {
  return *(const bf16x8*)(s + (row << 6) + ((kseg ^ (row & 7)) << 3));
}

// convert one 8-float chunk of the shared/expert weights to bf16
__device__ __forceinline__ void cvt_chunk(int chunk,
                                          const float* cSfc, const float* cSproj,
                                          const float* cEfc, const float* cEproj,
                                          u16* oSfc, u16* oSproj,
                                          u16* oEfc, u16* oEproj) {
  const float* in;
  u16* ou;
  int loc;
  if (chunk < 131072)       { in = cSfc;   ou = oSfc;   loc = chunk; }
  else if (chunk < 262144)  { in = cSproj; ou = oSproj; loc = chunk - 131072; }
  else if (chunk < 1310720) { in = cEfc;   ou = oEfc;   loc = chunk - 262144; }
  else                      { in = cEproj; ou = oEproj; loc = chunk - 1310720; }
  size_t i = (size_t)loc * 8;
  float4 a = *(const float4*)(in + i);
  float4 bb = *(const float4*)(in + i + 4);
  u16 r[8] = {f2b(a.x), f2b(a.y), f2b(a.z), f2b(a.w),
              f2b(bb.x), f2b(bb.y), f2b(bb.z), f2b(bb.w)};
  *(bf16x8*)(ou + i) = *(bf16x8*)r;
}

// ---------------- RMSNorm -> split bf16 (hi/lo) + fused ve-gates ----------------
// blocks >= NTOK convert QKVO weights to split bf16 (one 8-float chunk per thread).
__global__ __launch_bounds__(256) void rmsnorm_split_k(const float* __restrict__ in,
                                                       u16* __restrict__ hio,
                                                       u16* __restrict__ loo,
                                                       const float* __restrict__ gW,
                                                       float* __restrict__ gates,
                                                       const float* __restrict__ p0,
                                                       const float* __restrict__ p1,
                                                       const float* __restrict__ p2,
                                                       const float* __restrict__ p3,
                                                       u16* __restrict__ h0, u16* __restrict__ l0,
                                                       u16* __restrict__ h1, u16* __restrict__ l1,
                                                       u16* __restrict__ h2, u16* __restrict__ l2,
                                                       u16* __restrict__ h3, u16* __restrict__ l3) {
  const int bid = blockIdx.x;
  const int t = threadIdx.x;
  if (bid >= NTOK) {
    int chunk = (bid - NTOK) * 256 + t;
    const float* inw; u16* ho; u16* lo2; int loc;
    if (chunk < 131072)      { inw = p0; ho = h0; lo2 = l0; loc = chunk; }
    else if (chunk < 163840) { inw = p1; ho = h1; lo2 = l1; loc = chunk - 131072; }
    else if (chunk < 196608) { inw = p2; ho = h2; lo2 = l2; loc = chunk - 163840; }
    else                     { inw = p3; ho = h3; lo2 = l3; loc = chunk - 196608; }
    size_t i = (size_t)loc * 8;
    float v[8];
    *(float4*)v = *(const float4*)(inw + i);
    *(float4*)(v + 4) = *(const float4*)(inw + i + 4);
    u16 hh[8], ll[8];
#pragma unroll
    for (int j = 0; j < 8; ++j) {
      hh[j] = f2b(v[j]);
      ll[j] = f2b(v[j] - b2f(hh[j]));
    }
    *(bf16x8*)(ho + i) = *(bf16x8*)hh;
    *(bf16x8*)(lo2 + i) = *(bf16x8*)ll;
    return;
  }
  const int rowi = bid;
  float4 v = ((const float4*)(in + (size_t)rowi * CC))[t];
  float ss = v.x * v.x + v.y * v.y + v.z * v.z + v.w * v.w;
#pragma unroll
  for (int off = 32; off; off >>= 1) ss += __shfl_down(ss, off, 64);
  __shared__ float red[4];
  __shared__ float hshare[32];
  if ((t & 63) == 0) red[t >> 6] = ss;
  __syncthreads();
  float tot = red[0] + red[1] + red[2] + red[3];
  float sc = rsqrtf(tot * (1.0f / CC) + EPSF);
  float o[4] = {v.x * sc, v.y * sc, v.z * sc, v.w * sc};
  u16 h[4], l[4];
#pragma unroll
  for (int j = 0; j < 4; ++j) {
    h[j] = f2b(o[j]);
    l[j] = f2b(o[j] - b2f(h[j]));
  }
  *(u16x4*)(hio + (size_t)rowi * CC + t * 4) = *(u16x4*)h;
  *(u16x4*)(loo + (size_t)rowi * CC + t * 4) = *(u16x4*)l;
  if (t < 8) *(float4*)&hshare[t << 2] = *(float4*)o;
  __syncthreads();
  if (t < 4) {
    const float* gw = gW + (t << 5);
    float dot = 0.f;
#pragma unroll
    for (int j = 0; j < 32; ++j) dot += hshare[j] * gw[j];
    gates[(rowi << 2) + t] = 2.f / (1.f + __expf(-dot));
  }
}

// ---------------- RMSNorm(x2) -> bf16 h2 + fp32 router logits ----------------
__global__ __launch_bounds__(256) void rmsnorm_logits_k(const float* __restrict__ in,
                                                        u16* __restrict__ b16o,
                                                        const float* __restrict__ rW,
                                                        float* __restrict__ logits) {
  const int rowi = blockIdx.x;
  const int t = threadIdx.x;
  float4 v = ((const float4*)(in + (size_t)rowi * CC))[t];
  float ss = v.x * v.x + v.y * v.y + v.z * v.z + v.w * v.w;
#pragma unroll
  for (int off = 32; off; off >>= 1) ss += __shfl_down(ss, off, 64);
  __shared__ float red[4];
  __shared__ float red2[8][4];
  if ((t & 63) == 0) red[t >> 6] = ss;
  __syncthreads();
  float tot = red[0] + red[1] + red[2] + red[3];
  float sc = rsqrtf(tot * (1.0f / CC) + EPSF);
  float o[4] = {v.x * sc, v.y * sc, v.z * sc, v.w * sc};
  u16 h[4] = {f2b(o[0]), f2b(o[1]), f2b(o[2]), f2b(o[3])};
  *(u16x4*)(b16o + (size_t)rowi * CC + t * 4) = *(u16x4*)h;
  const float* rwp = rW + (t << 2);
  float part[8];
#pragma unroll
  for (int e = 0; e < 8; ++e) {
    const float* w = rwp + (e << 10);
    part[e] = o[0] * w[0] + o[1] * w[1] + o[2] * w[2] + o[3] * w[3];
  }
  const int wid = t >> 6;
#pragma unroll
  for (int e = 0; e < 8; ++e) {
    float p = part[e];
#pragma unroll
    for (int off = 32; off; off >>= 1) p += __shfl_down(p, off, 64);
    if ((t & 63) == 0) red2[e][wid] = p;
  }
  __syncthreads();
  if (t < 8) logits[rowi * 8 + t] = red2[t][0] + red2[t][1] + red2[t][2] + red2[t][3];
}

// ---------------- bf16 MFMA GEMM: C[M,N] = A[M,K] @ W[N,K]^T ----------------
// 128x64 tile, BK=64, 4 waves of 32rows x 64cols (acc[2][4]). Single-buffer staging.
// MODE:
// 4 gathered A, relu^2 bf16 out (expert fc; e==8 -> shared: identity gather, Wk1 weights)
// 5 gathered rows, w*atomicAdd f32 (expert proj; e==8 -> shared: w=1, Wk1 weights)
// 6 split(3-mfma), f32 x2 = v+addv, also pre-init out ((float*)Cb)
// 11 split fused QKV: N=1536 col-space; Q->rope+rms, K->rope+rms, V->gate (transposed store)
// Modes 4/5 remap blockIdx.z so the shared expert (largest stripe) dispatches FIRST.
template <int MODE>
__global__ __launch_bounds__(256) void gemm_bf_k(
    const u16* __restrict__ A, const u16* __restrict__ A2,
    const u16* __restrict__ Wt, const u16* __restrict__ W2,
    const u16* __restrict__ Wk1, const u16* __restrict__ Wk2,
    const u16* __restrict__ Wv1, const u16* __restrict__ Wv2,
    float* __restrict__ Cf, u16* __restrict__ Cb,
    u16* __restrict__ Ck, u16* __restrict__ Cv,
    const float* __restrict__ addv, int N, int K,
    const int* __restrict__ offsets, const int* __restrict__ counts,
    const int* __restrict__ tok_idx, const float* __restrict__ tok_w,
    const float* __restrict__ cosb, const float* __restrict__ sinb,
    const float* __restrict__ gates, const float* __restrict__ vein) {
  constexpr bool SPLIT = (MODE == 6 || MODE == 11);
  __shared__ __align__(16) u16 Asw[SPLIT ? 16384 : 8192];
  __shared__ __align__(16) u16 Bsw[SPLIT ? 8192 : 4096];
  const int t = threadIdx.x;
  const int lane = t & 63;
  const int l15 = lane & 15, hi = lane >> 4;
  const int wave = t >> 6;
  const int e = (MODE == 4 || MODE == 5)
                    ? ((blockIdx.z == 0) ? 8 : (int)blockIdx.z - 1)  // shared expert first
                    : (int)blockIdx.z;
  const int mt = blockIdx.y << 7;
  const int bn = blockIdx.x << 6;
  int base = 0, cnt = 0;
  if (MODE == 4 || MODE == 5) {
    cnt = (e == 8) ? NTOK : counts[e];
    if (mt >= cnt) return;
    base = (e == 8) ? 8192 : offsets[e];
  }
  const int r8 = t >> 3;
  const int ksg = (t & 7) ^ (r8 & 7);  // inverse-swizzled global k-segment
  const u16* asrc[4];
  const u16* bsrc[2];
  const u16* asrc2[4];
  const u16* bsrc2[2];
  // weight selection
  const u16* W1p = Wt;
  if (MODE == 4 || MODE == 5) W1p = (e == 8) ? Wk1 : Wt + ((size_t)e << 20);
  const u16* W2p = W2;
  int wrow = bn;
  if (MODE == 11) {
    if (bn >= 1280)      { W1p = Wv1; W2p = Wv2; wrow = bn - 1280; }
    else if (bn >= 1024) { W1p = Wk1; W2p = Wk2; wrow = bn - 1024; }
  }
#pragma unroll
  for (int g = 0; g < 4; ++g) {
    int rl = (g << 5) + r8;
    int arow;
    if (MODE == 4) {
      int rr = mt + rl; if (rr > cnt - 1) rr = cnt - 1;
      arow = (e == 8) ? rr : tok_idx[base + rr];
    } else if (MODE == 5) {
      int rr = mt + rl; if (rr > cnt - 1) rr = cnt - 1;
      arow = base + rr;
    } else {
      arow = mt + rl;
    }
    size_t ao = (size_t)arow * K + (ksg << 3);
    asrc[g] = A + ao;
    if (SPLIT) asrc2[g] = A2 + ao;
  }
#pragma unroll
  for (int g = 0; g < 2; ++g) {
    size_t bo = (size_t)(wrow + (g << 5) + r8) * K + (ksg << 3);
    bsrc[g] = W1p + bo;
    if (SPLIT) bsrc2[g] = W2p + bo;
  }
  f32x4 acc[2][4] = {};
  const int nkt = K >> 6;
  for (int kt = 0; kt < nkt; ++kt) {
    __syncthreads();
    const int ko = kt << 6;
#pragma unroll
    for (int g = 0; g < 4; ++g) {
      int co = ((g << 8) + t) << 3;
      gload16(asrc[g] + ko, &Asw[co]);
      if (SPLIT) gload16(asrc2[g] + ko, &Asw[8192 + co]);
    }
#pragma unroll
    for (int g = 0; g < 2; ++g) {
      int co = ((g << 8) + t) << 3;
      gload16(bsrc[g] + ko, &Bsw[co]);
      if (SPLIT) gload16(bsrc2[g] + ko, &Bsw[4096 + co]);
    }
    __syncthreads();
#pragma unroll
    for (int kk = 0; kk < 2; ++kk) {
      bf16x8 ah[2], bh[4];
#pragma unroll
      for (int mi = 0; mi < 2; ++mi)
        ah[mi] = ldsf(Asw, (wave << 5) + (mi << 4) + l15, (kk << 2) + hi);
#pragma unroll
      for (int nj = 0; nj < 4; ++nj)
        bh[nj] = ldsf(Bsw, (nj << 4) + l15, (kk << 2) + hi);
#pragma unroll
      for (int mi = 0; mi < 2; ++mi)
#pragma unroll
        for (int nj = 0; nj < 4; ++nj)
          acc[mi][nj] = __builtin_amdgcn_mfma_f32_16x16x32_bf16(ah[mi], bh[nj], acc[mi][nj], 0, 0, 0);
      if (SPLIT) {
        bf16x8 al[2], bl[4];
#pragma unroll
        for (int mi = 0; mi < 2; ++mi)
          al[mi] = ldsf(Asw + 8192, (wave << 5) + (mi << 4) + l15, (kk << 2) + hi);
#pragma unroll
        for (int nj = 0; nj < 4; ++nj)
          bl[nj] = ldsf(Bsw + 4096, (nj << 4) + l15, (kk << 2) + hi);
#pragma unroll
        for (int mi = 0; mi < 2; ++mi)
#pragma unroll
          for (int nj = 0; nj < 4; ++nj) {
            acc[mi][nj] = __builtin_amdgcn_mfma_f32_16x16x32_bf16(ah[mi], bl[nj], acc[mi][nj], 0, 0, 0);
            acc[mi][nj] = __builtin_amdgcn_mfma_f32_16x16x32_bf16(al[mi], bh[nj], acc[mi][nj], 0, 0, 0);
          }
      }
    }
  }
  // ---- epilogues (C/D layout: col=l15, row=hi*4+r; block col span = bn..bn+63) ----
  if (MODE == 11) {
    if (bn < 1280) {
      // rope + per-head rmsnorm (Q or K); block's 64 cols = one head
      u16* outp = (bn < 1024) ? Cb : Ck;
      const int stride = (bn < 1024) ? 1024 : 256;
      const int cbase = (bn < 1024) ? bn : (bn - 1024);
#pragma unroll
      for (int mi = 0; mi < 2; ++mi) {
#pragma unroll
        for (int r = 0; r < 4; ++r) {
          int row = mt + (wave << 5) + (mi << 4) + (hi << 2) + r;
          int tpos = row & (TT - 1);
          const float* cp = cosb + (tpos << 5);
          const float* sp = sinb + (tpos << 5);
          float c0 = cp[l15], s0 = sp[l15];
          float c1 = cp[16 + l15], s1 = sp[16 + l15];
          float a0 = acc[mi][0][r], a1 = acc[mi][1][r];
          float b0 = acc[mi][2][r], b1 = acc[mi][3][r];
          float r00 = a0 * c0 + b0 * s0;
          float r01 = a1 * c1 + b1 * s1;
          float r10 = b0 * c0 - a0 * s0;
          float r11 = b1 * c1 - a1 * s1;
          float ss = r00 * r00 + r01 * r01 + r10 * r10 + r11 * r11;
          ss += __shfl_xor(ss, 1, 64); ss += __shfl_xor(ss, 2, 64);
          ss += __shfl_xor(ss, 4, 64); ss += __shfl_xor(ss, 8, 64);
          float scn = rsqrtf(ss * (1.f / 64.f) + EPSF);
          u16* qp = outp + (size_t)row * stride + cbase;
          qp[l15]      = f2b(r00 * scn);
          qp[16 + l15] = f2b(r01 * scn);
          qp[32 + l15] = f2b(r10 * scn);
          qp[48 + l15] = f2b(r11 * scn);
        }
      }
    } else {
      // V: gate epilogue, store TRANSPOSED: Cv[((b*4+kvh)*64 + d)*2048 + tok_in_b]
      const int cbase = bn - 1280;
      const int kvh = cbase >> 6;
#pragma unroll
      for (int mi = 0; mi < 2; ++mi) {
#pragma unroll
        for (int r = 0; r < 4; ++r) {
          int row = mt + (wave << 5) + (mi << 4) + (hi << 2) + r;
          float g = gates[(row << 2) + kvh];
          const float* vep = vein + ((size_t)row << 8) + cbase;
          size_t vb_base = ((size_t)(((row >> 11) << 2) + kvh) << 17) + (row & (TT - 1));
#pragma unroll
          for (int nj = 0; nj < 4; ++nj) {
            int d = (nj << 4) + l15;
            Cv[vb_base + ((size_t)d << 11)] = f2b(acc[mi][nj][r] + g * vep[d]);
          }
        }
      }
    }
    return;
  }
#pragma unroll
  for (int mi = 0; mi < 2; ++mi) {
#pragma unroll
    for (int r = 0; r < 4; ++r) {
      int rl = (wave << 5) + (mi << 4) + (hi << 2) + r;
      if (MODE == 4 || MODE == 5) {
        int rr = mt + rl;
        if (rr >= cnt) continue;
        if (MODE == 4) {
          size_t ro = (size_t)(base + rr) * N;
#pragma unroll
          for (int nj = 0; nj < 4; ++nj) {
            float v = acc[mi][nj][r];
            v = v > 0.f ? v * v : 0.f;
            Cb[ro + bn + (nj << 4) + l15] = f2b(v);
          }
        } else {
          int tok = (e == 8) ? rr : tok_idx[base + rr];
          float w = (e == 8) ? 1.0f : tok_w[base + rr];
          size_t ro = (size_t)tok * N;
#pragma unroll
          for (int nj = 0; nj < 4; ++nj)
            atomicAdd(&Cf[ro + bn + (nj << 4) + l15], acc[mi][nj][r] * w);
        }
      } else {  // MODE 6
        size_t ro = (size_t)(mt + rl) * N;
        float* outp = (float*)Cb;
#pragma unroll
        for (int nj = 0; nj < 4; ++nj) {
          int col = bn + (nj << 4) + l15;
          float v = acc[mi][nj][r] + addv[ro + col];
          Cf[ro + col] = v;
          outp[ro + col] = v;
        }
      }
    }
  }
}

// ---------------- flash attention, split-K, dbuf K/V staging; idle+short blocks convert weights ----------------
// FROZEN NUMERICS: max-tracked online softmax, exact op order from rounds 13/15/16/18/19 (passing).
// grid = (128 q-frags, 4 kvh, 4 = b*2+seg), 256 threads = 4 waves; wave w = head kvh*4+w.
// 512 (qf<64, seg=1) blocks: dedicated converters (12 iters each).
// 512 (qf<64, seg=0) blocks: attn then 6 converter iters (backfills the tail).
__global__ __launch_bounds__(256) void attn_mfma_k(const u16* __restrict__ qb,
                                                   const u16* __restrict__ kb,
                                                   const u16* __restrict__ vbT,
                                                   u16* __restrict__ yh,
                                                   u16* __restrict__ yl,
                                                   const int* __restrict__ wszp,
                                                   float* __restrict__ po,
                                                   float* __restrict__ pml,
                                                   const float* __restrict__ cSfc,
                                                   const float* __restrict__ cSproj,
                                                   const float* __restrict__ cEfc,
                                                   const float* __restrict__ cEproj,
                                                   u16* __restrict__ oSfc,
                                                   u16* __restrict__ oSproj,
                                                   u16* __restrict__ oEfc,
                                                   u16* __restrict__ oEproj) {
  const int z = blockIdx.z;
  const int b = z >> 1, seg = z & 1;
  const int kvh = blockIdx.y;
  const int qf = 127 - (int)blockIdx.x;  // LPT: longest first
  const int t = threadIdx.x;
  if (qf < 64 && seg) {
    // dedicated converter block: 12 iters x 256 threads x 8 floats
    const int cid = (((b << 2) + kvh) << 6) + ((int)blockIdx.x - 64);
    int chunk = cid * 3072 + t;
#pragma unroll
    for (int it = 0; it < 12; ++it, chunk += 256)
      cvt_chunk(chunk, cSfc, cSproj, cEfc, cEproj, oSfc, oSproj, oEfc, oEproj);
    return;
  }
  const int Wn = *wszp;
  const int lane = t & 63, wave = t >> 6;
  const int h = (kvh << 2) + wave;
  const int l15 = lane & 15, hi = lane >> 4;

  __shared__ __align__(16) u16 Klds[2 * 4096];    // dbuf swizzled [key][d]
  __shared__ __align__(16) u16 Vt[2 * 4096];      // dbuf swizzled [d][key]
  __shared__ __align__(16) u16 Plds[4][16 * 64];  // per-wave swizzled [qrow][key]

  const int qrow0 = qf << 4;
  const int diag = qrow0 >> 6;
  int lo = qrow0 - Wn + 1;
  const int kt0f = lo > 0 ? (lo >> 6) : 0;
  int kt0 = kt0f, ktend = diag;
  if (qf >= 64) {
    int nt = diag - kt0f + 1;
    int mid = kt0f + (nt >> 1);
    if (seg == 0) ktend = mid - 1; else kt0 = mid;
  }

  bf16x8 aQ0, aQ1;
  {
    const u16* qp = qb + ((size_t)((b << 11) + qrow0 + l15) << 10) + (h << 6) + (hi << 3);
    aQ0 = *(const bf16x8*)qp;
    aQ1 = *(const bf16x8*)(qp + 32);
  }
  f32x4 o[4] = {};
  float mrow[4] = {-INFINITY, -INFINITY, -INFINITY, -INFINITY};
  float lrow[4] = {0.f, 0.f, 0.f, 0.f};

  const int kr0 = t >> 3, kc = t & 7;  // staging coords (row 0..31, 8-elem col chunk)
  const u16* vbase = vbT + ((size_t)((b << 2) + kvh) << 17);

  // prologue: stage kt0 into buf 0
#pragma unroll
  for (int i = 0; i < 2; ++i) {
    int row = kr0 + (i << 5);
    int scol = (kc ^ (row & 7)) << 3;
    gload16(kb + ((size_t)((b << 11) + (kt0 << 6) + row) << 8) + (kvh << 6) + scol,
            &Klds[(t << 3) + (i << 11)]);
    gload16(vbase + ((size_t)row << 11) + (kt0 << 6) + scol,
            &Vt[(t << 3) + (i << 11)]);
  }
  int cur = 0;

  for (int kt = kt0; kt <= ktend; ++kt) {
    __syncthreads();  // buf[cur] loads drained; prior reads of buf[cur^1] retired
    if (kt + 1 <= ktend) {
      const int nb = (cur ^ 1) << 12;
#pragma unroll
      for (int i = 0; i < 2; ++i) {
        int row = kr0 + (i << 5);
        int scol = (kc ^ (row & 7)) << 3;
        gload16(kb + ((size_t)((b << 11) + ((kt + 1) << 6) + row) << 8) + (kvh << 6) + scol,
                &Klds[nb + (t << 3) + (i << 11)]);
        gload16(vbase + ((size_t)row << 11) + ((kt + 1) << 6) + scol,
                &Vt[nb + (t << 3) + (i << 11)]);
      }
    }
    const u16* Kb = Klds + (cur << 12);
    const u16* Vb = Vt + (cur << 12);

    // QK^T (setprio around MFMA cluster)
    float sv[4][4];
    __builtin_amdgcn_s_setprio(1);
#pragma unroll
    for (int kb4 = 0; kb4 < 4; ++kb4) {
      f32x4 S = {0.f, 0.f, 0.f, 0.f};
      bf16x8 B0 = ldsf(Kb, (kb4 << 4) + l15, hi);
      bf16x8 B1 = ldsf(Kb, (kb4 << 4) + l15, 4 + hi);
      S = __builtin_amdgcn_mfma_f32_16x16x32_bf16(aQ0, B0, S, 0, 0, 0);
      S = __builtin_amdgcn_mfma_f32_16x16x32_bf16(aQ1, B1, S, 0, 0, 0);
#pragma unroll
      for (int r = 0; r < 4; ++r) sv[kb4][r] = S[r] * 0.125f;
    }
    __builtin_amdgcn_s_setprio(0);
    // masking only on diagonal / window-edge tiles (wave-uniform branch)
    if (kt == diag || kt == kt0f) {
#pragma unroll
      for (int kb4 = 0; kb4 < 4; ++kb4) {
        int key = (kt << 6) + (kb4 << 4) + l15;
#pragma unroll
        for (int r = 0; r < 4; ++r) {
          int qg = qrow0 + (hi << 2) + r;
          if (!(key <= qg && key > qg - Wn)) sv[kb4][r] = -INFINITY;
        }
      }
    }

    // online softmax (4 independent chains), guard-free exp
    float scl[4], pv[4][4];
#pragma unroll
    for (int r = 0; r < 4; ++r) {
      float mt2 = fmaxf(fmaxf(sv[0][r], sv[1][r]), fmaxf(sv[2][r], sv[3][r]));
      mt2 = fmaxf(mt2, __shfl_xor(mt2, 1, 64));
      mt2 = fmaxf(mt2, __shfl_xor(mt2, 2, 64));
      mt2 = fmaxf(mt2, __shfl_xor(mt2, 4, 64));
      mt2 = fmaxf(mt2, __shfl_xor(mt2, 8, 64));
      float mn = fmaxf(fmaxf(mrow[r], mt2), -1e30f);
      float sc = __expf(mrow[r] - mn);
      float rs = 0.f;
#pragma unroll
      for (int kb4 = 0; kb4 < 4; ++kb4) {
        float p = __expf(sv[kb4][r] - mn);
        pv[kb4][r] = p;
        rs += p;
      }
      rs += __shfl_xor(rs, 1, 64);
      rs += __shfl_xor(rs, 2, 64);
      rs += __shfl_xor(rs, 4, 64);
      rs += __shfl_xor(rs, 8, 64);
      mrow[r] = mn;
      lrow[r] = lrow[r] * sc + rs;
      scl[r] = sc;
    }

    // P -> wave-local swizzled LDS
#pragma unroll
    for (int kb4 = 0; kb4 < 4; ++kb4)
#pragma unroll
      for (int r = 0; r < 4; ++r) {
        int row16 = (hi << 2) + r;
        int seg2 = (kb4 << 1) + (l15 >> 3);
        Plds[wave][(row16 << 6) + ((seg2 ^ (row16 & 7)) << 3) + (l15 & 7)] = f2b(pv[kb4][r]);
      }
    // rescale O
#pragma unroll
    for (int df = 0; df < 4; ++df) {
      f32x4 t4 = o[df];
      t4[0] *= scl[0]; t4[1] *= scl[1]; t4[2] *= scl[2]; t4[3] *= scl[3];
      o[df] = t4;
    }
    // PV (setprio around MFMA cluster)
    __builtin_amdgcn_s_setprio(1);
#pragma unroll
    for (int ks = 0; ks < 2; ++ks) {
      bf16x8 Ap = ldsf(Plds[wave], l15, (ks << 2) + hi);
#pragma unroll
      for (int df = 0; df < 4; ++df) {
        bf16x8 Bv = ldsf(Vb, (df << 4) + l15, (ks << 2) + hi);
        o[df] = __builtin_amdgcn_mfma_f32_16x16x32_bf16(Ap, Bv, o[df], 0, 0, 0);
      }
    }
    __builtin_amdgcn_s_setprio(0);
    cur ^= 1;
  }

  if (qf < 64) {
    float inv[4];
#pragma unroll
    for (int r = 0; r < 4; ++r) inv[r] = lrow[r] > 0.f ? 1.f / lrow[r] : 0.f;
#pragma unroll
    for (int r = 0; r < 4; ++r) {
      size_t rbase = ((size_t)((b << 11) + qrow0 + (hi << 2) + r) << 10) + (h << 6) + l15;
#pragma unroll
      for (int df = 0; df < 4; ++df) {
        float fo = o[df][r] * inv[r];
        u16 hv = f2b(fo);
        yh[rbase + (df << 4)] = hv;
        yl[rbase + (df << 4)] = f2b(fo - b2f(hv));
      }
    }
    // backfill: short attn blocks (seg==0) convert 6 chunks each after their epilogue
    {
      const int cid = (((b << 2) + kvh) << 6) + ((int)blockIdx.x - 64);
      int chunk = 1572864 + cid * 1536 + t;  // tail region after dedicated converters
#pragma unroll
      for (int it = 0; it < 6; ++it, chunk += 256)
        cvt_chunk(chunk, cSfc, cSproj, cEfc, cEproj, oSfc, oSproj, oEfc, oEproj);
    }
  } else {
    const int sidx = (b << 1) + seg;
    const int prow0 = qrow0 - 1024;
#pragma unroll
    for (int r = 0; r < 4; ++r) {
      size_t pbase = ((size_t)(sidx * 1024 + prow0 + (hi << 2) + r) << 10) + (h << 6) + l15;
#pragma unroll
      for (int df = 0; df < 4; ++df) po[pbase + (df << 4)] = o[df][r];
    }
    if (l15 == 0) {
#pragma unroll
      for (int r = 0; r < 4; ++r) {
        size_t mb = ((size_t)(sidx * 1024 + prow0 + (hi << 2) + r) << 5) + (h << 1);
        pml[mb] = mrow[r];
        pml[mb + 1] = lrow[r];
      }
    }
  }
}

// ---------------- combine split-K partials -> y (max-tracked merge) ----------------
__global__ __launch_bounds__(256) void combine_k(const float* __restrict__ po,
                                                 const float* __restrict__ pml,
                                                 u16* __restrict__ yh,
                                                 u16* __restrict__ yl) {
  const int prow = blockIdx.x, b = blockIdx.y;
  const int t = threadIdx.x;
  const int h = t >> 4, d0 = (t & 15) << 2;
  const int s0 = b << 1, s1 = s0 + 1;
  size_t i0 = ((size_t)(s0 * 1024 + prow) << 5) + (h << 1);
  size_t i1 = ((size_t)(s1 * 1024 + prow) << 5) + (h << 1);
  float m0 = pml[i0], l0 = pml[i0 + 1];
  float m1 = pml[i1], l1 = pml[i1 + 1];
  float m = fmaxf(m0, m1);
  float sc0 = __expf(m0 - m), sc1 = __expf(m1 - m);
  float l = l0 * sc0 + l1 * sc1;
  float inv = l > 0.f ? 1.f / l : 0.f;
  size_t o0 = ((size_t)(s0 * 1024 + prow) << 10) + (h << 6) + d0;
  size_t o1 = ((size_t)(s1 * 1024 + prow) << 10) + (h << 6) + d0;
  float4 a = *(const float4*)&po[o0];
  float4 c = *(const float4*)&po[o1];
  float y0 = (a.x * sc0 + c.x * sc1) * inv;
  float y1 = (a.y * sc0 + c.y * sc1) * inv;
  float y2 = (a.z * sc0 + c.z * sc1) * inv;
  float y3 = (a.w * sc0 + c.w * sc1) * inv;
  u16 hv[4] = {f2b(y0), f2b(y1), f2b(y2), f2b(y3)};
  u16 lv[4] = {f2b(y0 - b2f(hv[0])), f2b(y1 - b2f(hv[1])),
               f2b(y2 - b2f(hv[2])), f2b(y3 - b2f(hv[3]))};
  size_t rbase = ((size_t)((b << 11) + 1024 + prow) << 10) + (h << 6) + d0;
  *(u16x4*)(yh + rbase) = *(u16x4*)hv;
  *(u16x4*)(yl + rbase) = *(u16x4*)lv;
}

// ---------------- fused router: top-2 + scan + scatter, one block ----------------
__global__ __launch_bounds__(256) void router_all_k(const float* __restrict__ logits,
                                                    const float* __restrict__ bias,
                                                    int* __restrict__ counts,
                                                    int* __restrict__ offsets,
                                                    int* __restrict__ tok_idx,
                                                    float* __restrict__ tok_w) {
  __shared__ int cnt[8], off[9], cnt2[8];
  const int t = threadIdx.x;
  if (t < 8) { cnt[t] = 0; cnt2[t] = 0; }
  __syncthreads();
  // phase 1: counts
  for (int k = 0; k < 16; ++k) {
    int n = t * 16 + k;
    float sel[8];
#pragma unroll
    for (int e2 = 0; e2 < 8; ++e2)
      sel[e2] = 1.f / (1.f + __expf(-logits[n * 8 + e2])) + bias[e2];
    int i1 = 0; float b1 = sel[0];
#pragma unroll
    for (int j = 1; j < 8; ++j) if (sel[j] > b1) { b1 = sel[j]; i1 = j; }
    int i2 = -1; float b2 = -INFINITY;
#pragma unroll
    for (int j = 0; j < 8; ++j) if (j != i1 && sel[j] > b2) { b2 = sel[j]; i2 = j; }
    atomicAdd(&cnt[i1], 1);
    atomicAdd(&cnt[i2], 1);
  }
  __syncthreads();
  // phase 2: scan
  if (t == 0) {
    int s = 0;
    for (int e2 = 0; e2 < 8; ++e2) { off[e2] = s; offsets[e2] = s; counts[e2] = cnt[e2]; s += cnt[e2]; }
    off[8] = s; offsets[8] = s;
  }
  __syncthreads();
  // phase 3: scatter (recompute top-2: bit-identical selection)
  for (int k = 0; k < 16; ++k) {
    int n = t * 16 + k;
    float sc[8], sel[8];
#pragma unroll
    for (int e2 = 0; e2 < 8; ++e2) {
      float sg = 1.f / (1.f + __expf(-logits[n * 8 + e2]));
      sc[e2] = sg;
      sel[e2] = sg + bias[e2];
    }
    int i1 = 0; float b1 = sel[0];
#pragma unroll
    for (int j = 1; j < 8; ++j) if (sel[j] > b1) { b1 = sel[j]; i1 = j; }
    int i2 = -1; float b2 = -INFINITY;
#pragma unroll
    for (int j = 0; j < 8; ++j) if (j != i1 && sel[j] > b2) { b2 = sel[j]; i2 = j; }
    float w1 = sc[i1], w2 = sc[i2];
    float invs = 1.f / (w1 + w2 + 1e-20f);
    int s1 = atomicAdd(&cnt2[i1], 1);
    int p1 = off[i1] + s1;
    tok_idx[p1] = n;
    tok_w[p1] = w1 * invs;
    int s2 = atomicAdd(&cnt2[i2], 1);
    int p2 = off[i2] + s2;
    tok_idx[p2] = n;
    tok_w[p2] = w2 * invs;
  }
}

extern "C" void kernel_launch(void* const* d_in, const int* in_sizes, int n_in,
                              void* d_out, int out_size, void* d_ws, size_t ws_size,
                              hipStream_t stream) {
  const float* x = (const float*)d_in[0];
  const float* ve = (const float*)d_in[1];
  const float* cosb = (const float*)d_in[2];
  const float* sinb = (const float*)d_in[3];
  const float* Wq = (const float*)d_in[4];
  const float* Wk = (const float*)d_in[5];
  const float* Wv = (const float*)d_in[6];
  const float* Wo = (const float*)d_in[7];
  const float* gW = (const float*)d_in[8];
  const float* routerW = (const float*)d_in[9];
  const float* bias = (const float*)d_in[10];
  const float* Wsfc = (const float*)d_in[11];
  const float* Wsproj = (const float*)d_in[12];
  const float* Wefc = (const float*)d_in[13];
  const float* Weproj = (const float*)d_in[14];
  const int* wsz = (const int*)d_in[15];
  float* out = (float*)d_out;
  char* WS = (char*)d_ws;

  // ---- workspace layout (byte offsets), peak ~91 MiB ----
  u16* Wefc_b   = (u16*)(WS + 0);          // 16 MiB
  u16* Weproj_b = (u16*)(WS + 16777216);   // 16 MiB
  u16* Wsfc_b   = (u16*)(WS + 33554432);   // 2 MiB
  u16* Wsproj_b = (u16*)(WS + 35651584);   // 2 MiB
  u16* Wq_hi    = (u16*)(WS + 37748736);   // 2 MiB
  u16* Wq_lo    = (u16*)(WS + 39845888);   // 2 MiB
  u16* Wk_hi    = (u16*)(WS + 41943040);   // 0.5 MiB
  u16* Wk_lo    = (u16*)(WS + 42467328);   // 0.5 MiB
  u16* Wv_hi    = (u16*)(WS + 42991616);   // 0.5 MiB
  u16* Wv_lo    = (u16*)(WS + 43515904);   // 0.5 MiB
  u16* Wo_hi    = (u16*)(WS + 44040192);   // 2 MiB
  u16* Wo_lo    = (u16*)(WS + 46137344);   // 2 MiB
  u16* h_hi     = (u16*)(WS + 48234496);   // 8 MiB [dead after QKV]
  u16* h_lo     = (u16*)(WS + 56623104);   // 8 MiB [dead after QKV]
  u16* qb       = (u16*)(WS + 65011712);   // 8 MiB [dead after attn]
  u16* kb       = (u16*)(WS + 73400320);   // 2 MiB [dead after attn]
  u16* vb       = (u16*)(WS + 75497472);   // 2 MiB [dead after attn] (transposed layout)
  u16* y_hi     = (u16*)(WS + 77594624);   // 8 MiB [dead after Wo gemm]
  u16* y_lo     = (u16*)(WS + 85983232);   // 8 MiB [dead after Wo gemm]
  float* po     = (float*)(WS + 48234496); // 16 MiB over h_hi+h_lo [attn partials; dead after combine]
  float* x2     = (float*)(WS + 48234496); // 16 MiB over po [written post-combine, dead post-logits]
  u16* h2_b     = (u16*)(WS + 85983232);   // 8 MiB over y_lo [written post-Wo]
  u16* he_b     = (u16*)(WS + 48234496);   // 24 MiB over x2+qb [written post-logits], 12288 rows
  float* gates  = (float*)(WS + 94371840); // 64 KiB
  float* logits = (float*)(WS + 94437376); // 128 KiB
  int* meta     = (int*)(WS + 94568448);
  int* counts   = meta;
  int* offsets  = meta + 16;
  int* tok_idx  = meta + 16416;
  float* tok_w  = (float*)(meta + 24608);
  float* pml    = (float*)(WS + 94703616); // 512 KiB attn partial m/l

  // h = rmsnorm(x) split + fused gates; extra 1280 blocks convert QKVO weights (split)
  rmsnorm_split_k<<<NTOK + 1280, 256, 0, stream>>>(x, h_hi, h_lo, gW, gates,
      Wq, Wk, Wv, Wo,
      Wq_hi, Wq_lo, Wk_hi, Wk_lo, Wv_hi, Wv_lo, Wo_hi, Wo_lo);
  // fused QKV split gemm (N=1536, 128x64 tiles) with per-head epilogues (V stored transposed)
  gemm_bf_k<11><<<dim3(24, 32), 256, 0, stream>>>(
      h_hi, h_lo, Wq_hi, Wq_lo, Wk_hi, Wk_lo, Wv_hi, Wv_lo,
      nullptr, qb, kb, vb, nullptr, 1536, 1024,
      nullptr, nullptr, nullptr, nullptr, cosb, sinb, gates, ve);
  // attention (split-K for rows >= 1024) -> y + partials; idle+short blocks convert expert weights
  attn_mfma_k<<<dim3(128, 4, 4), 256, 0, stream>>>(qb, kb, vb, y_hi, y_lo, wsz, po, pml,
      Wsfc, Wsproj, Wefc, Weproj, Wsfc_b, Wsproj_b, Wefc_b, Weproj_b);
  combine_k<<<dim3(1024, 2), 256, 0, stream>>>(po, pml, y_hi, y_lo);
  // x2 = x + y @ Wo^T (split, 128x64 tiles); also pre-init out = x2
  gemm_bf_k<6><<<dim3(16, 32), 256, 0, stream>>>(
      y_hi, y_lo, Wo_hi, Wo_lo, nullptr, nullptr, nullptr, nullptr,
      x2, (u16*)out, nullptr, nullptr, x, 1024, 1024,
      nullptr, nullptr, nullptr, nullptr, nullptr, nullptr, nullptr, nullptr);
  // h2 = rmsnorm(x2) -> bf16 + fp32 router logits
  rmsnorm_logits_k<<<NTOK, 256, 0, stream>>>(x2, h2_b, routerW, logits);
  // fused router (top-2 + scan + scatter), one block
  router_all_k<<<1, 256, 0, stream>>>(logits, bias, counts, offsets, tok_idx, tok_w);
  // experts (z=0 shared first, z=1..8 routed), 128x64 tiles, fc then proj (atomicAdd into out)
  gemm_bf_k<4><<<dim3(16, 32, 9), 256, 0, stream>>>(
      h2_b, nullptr, Wefc_b, nullptr, Wsfc_b, nullptr, nullptr, nullptr,
      nullptr, he_b, nullptr, nullptr, nullptr, 1024, 1024,
      offsets, counts, tok_idx, nullptr, nullptr, nullptr, nullptr, nullptr);
  gemm_bf_k<5><<<dim3(16, 32, 9), 256, 0, stream>>>(
      he_b, nullptr, Weproj_b, nullptr, Wsproj_b, nullptr, nullptr, nullptr,
      out, nullptr, nullptr, nullptr, nullptr, 1024, 1024,
      offsets, counts, tok_idx, tok_w, nullptr, nullptr, nullptr, nullptr);
}